// Round 2
// baseline (4615.357 us; speedup 1.0000x reference)
//
#include <hip/hip_runtime.h>
#include <hip/hip_bf16.h>

typedef __hip_bfloat16 bf16;

__device__ __forceinline__ float tof(float v){ return v; }
__device__ __forceinline__ float tof(bf16 v){ return __bfloat162float(v); }
__device__ __forceinline__ void sto(float* p, float v){ *p = v; }
__device__ __forceinline__ void sto(bf16* p, float v){ *p = __float2bfloat16(v); }

// ---------- audio embedding: out[t,l] = b[l] + sum_k hs[t,k] w[k,l] ----------
__global__ __launch_bounds__(64) void k_audio(const float* __restrict__ hs,
    const float* __restrict__ w, const float* __restrict__ b, float* __restrict__ out)
{
    int t = blockIdx.x, l = threadIdx.x;
    float acc = b[l];
    const float* h = hs + t*768;
    #pragma unroll 4
    for (int k = 0; k < 768; k++) acc += h[k] * w[k*64 + l];
    out[t*64 + l] = acc;
}

// ---------- enc_lat: actor_emb[l] = b[l] + sum_{k<4096} flat[k] w[k,l] ----------
__global__ __launch_bounds__(256) void k_enclat(const float* __restrict__ flat,
    const float* __restrict__ w, const float* __restrict__ b, float* __restrict__ out)
{
    __shared__ float red[256];
    int l = blockIdx.x, tid = threadIdx.x;
    float acc = 0.f;
    for (int k = tid; k < 4096; k += 256) acc += flat[k] * w[k*64 + l];
    red[tid] = acc; __syncthreads();
    for (int s = 128; s > 0; s >>= 1){ if (tid < s) red[tid] += red[tid+s]; __syncthreads(); }
    if (tid == 0) out[l] = red[0] + b[l];
}

// ---------- dec_lin fused with latent concat ----------
__global__ __launch_bounds__(256) void k_declin(const float* __restrict__ ae,
    const float* __restrict__ pe, const float* __restrict__ w, const float* __restrict__ b,
    float* __restrict__ out)
{
    int n = blockIdx.x*256 + threadIdx.x;   // 0..4095
    int t = blockIdx.y;                     // 0..63
    float acc = b[n];
    const float* a = ae + t*64;
    #pragma unroll 8
    for (int k = 0; k < 64; k++) acc += a[k]  * w[k*4096 + n];
    #pragma unroll 8
    for (int k = 0; k < 64; k++) acc += pe[k] * w[(64+k)*4096 + n];
    out[(size_t)t*4096 + n] = acc;
}

// ---------- generic 3-tap pool: out[t,r,c] = sum_{k<3} val[3r+k] * x[t,col[3r+k],c] ----------
template<typename TOUT>
__global__ __launch_bounds__(256) void k_pool(const float* __restrict__ xin,
    const int* __restrict__ col, const float* __restrict__ val, TOUT* __restrict__ out,
    int total, int cmask, int cs, int vomask, int vos, int Vi)
{
    int i = blockIdx.x*256 + threadIdx.x;
    if (i >= total) return;
    int c  = i & cmask;
    int rv = i >> cs;
    int r  = rv & vomask;
    int t  = rv >> vos;
    int C  = cmask + 1;
    const float* xt = xin + (size_t)t * Vi * C;
    int r3 = 3*r;
    int j0 = col[r3], j1 = col[r3+1], j2 = col[r3+2];
    float acc = val[r3  ] * xt[(size_t)j0*C + c]
              + val[r3+1] * xt[(size_t)j1*C + c]
              + val[r3+2] * xt[(size_t)j2*C + c];
    sto(&out[i], acc);
}

// ---------- generic spiral conv + ELU ----------
// out[t,v,o] = elu(b[o] + sum_{s,c} x[t, spiral[v,s], c] * w[(s*C+c)*O + o])
// block = MT vertices x O2 threads (each thread does outputs 2o, 2o+1), 256 threads.
// Gathered rows staged in LDS with padded stride KP (KP%4==0 keeps float4 alignment).
template<typename TIN>
__global__ __launch_bounds__(256) void k_conv(const TIN* __restrict__ xin,
    const int* __restrict__ spiral, const float* __restrict__ w, const float* __restrict__ bias,
    float* __restrict__ out, int TV, int V, int vshift, int C, int O2, int o2shift,
    int K, int KP, int MT)
{
    extern __shared__ float lds[];
    const int S = 9;
    int tid = threadIdx.x;
    int O = O2 << 1;
    int gmbase = blockIdx.x * MT;

    // cooperative gather: lds[m*KP + k] = x[t, spiral[v,s], c],  k = s*C + c
    int total = MT * K;
    for (int e = tid; e < total; e += 256){
        int m = e / K, k = e - m*K;
        int gm = gmbase + m;
        if (gm < TV){
            int t = gm >> vshift, v = gm & (V-1);
            int s = k / C, c = k - s*C;
            int j = spiral[v*S + s];
            lds[m*KP + k] = tof(xin[((size_t)t*V + j)*C + c]);
        }
    }
    __syncthreads();

    int m = tid >> o2shift;
    int o = tid & (O2 - 1);
    int gm = gmbase + m;
    if (gm >= TV) return;
    const float* g  = lds + m*KP;
    const float* wp = w + 2*o;
    float acc0 = bias[2*o];
    float acc1 = bias[2*o+1];
    int K4 = K & ~3;
    for (int k = 0; k < K4; k += 4){
        float4 g4 = *(const float4*)(g + k);
        float2 w0 = *(const float2*)(wp + (size_t)k    *O);
        float2 w1 = *(const float2*)(wp + (size_t)(k+1)*O);
        float2 w2 = *(const float2*)(wp + (size_t)(k+2)*O);
        float2 w3 = *(const float2*)(wp + (size_t)(k+3)*O);
        acc0 += g4.x*w0.x + g4.y*w1.x + g4.z*w2.x + g4.w*w3.x;
        acc1 += g4.x*w0.y + g4.y*w1.y + g4.z*w2.y + g4.w*w3.y;
    }
    for (int k = K4; k < K; k++){
        float gv = g[k];
        acc0 += gv * wp[(size_t)k*O];
        acc1 += gv * wp[(size_t)k*O + 1];
    }
    acc0 = acc0 > 0.f ? acc0 : __expf(acc0) - 1.f;
    acc1 = acc1 > 0.f ? acc1 : __expf(acc1) - 1.f;
    float2 r; r.x = acc0; r.y = acc1;
    *(float2*)(out + (size_t)gm*O + 2*o) = r;
}

// ---------- final conv (O=3, no ELU) fused with actor residual, f32 out ----------
__global__ __launch_bounds__(256) void k_outconv(const float* __restrict__ xin,
    const int* __restrict__ spiral, const float* __restrict__ w, const float* __restrict__ bias,
    const float* __restrict__ actor, float* __restrict__ out, int TV, int vshift, int C)
{
    int i = blockIdx.x*256 + threadIdx.x;
    if (i >= TV) return;
    int V = 1 << vshift;
    int v = i & (V-1);
    int t = i >> vshift;
    const float* xt = xin + (size_t)t * V * C;
    float a0 = bias[0], a1 = bias[1], a2 = bias[2];
    for (int s = 0; s < 9; s++){
        int j = spiral[v*9 + s];
        const float* xr = xt + (size_t)j*C;
        const float* wr = w + s*C*3;
        #pragma unroll 8
        for (int c = 0; c < C; c++){
            float xv = xr[c];
            a0 += xv * wr[c*3];
            a1 += xv * wr[c*3+1];
            a2 += xv * wr[c*3+2];
        }
    }
    a0 += actor[v*3]; a1 += actor[v*3+1]; a2 += actor[v*3+2];
    out[(size_t)i*3]   = a0;
    out[(size_t)i*3+1] = a1;
    out[(size_t)i*3+2] = a2;
}

extern "C" void kernel_launch(void* const* d_in, const int* in_sizes, int n_in,
                              void* d_out, int out_size, void* d_ws, size_t ws_size,
                              hipStream_t stream)
{
    (void)n_in; (void)out_size; (void)ws_size;
    const float* hs        = (const float*)d_in[0];
    const float* actor     = (const float*)d_in[1];
    const float* audio_w   = (const float*)d_in[2];
    const float* audio_b   = (const float*)d_in[3];
    const float* enc_w[4]  = {(const float*)d_in[4],(const float*)d_in[6],(const float*)d_in[8],(const float*)d_in[10]};
    const float* enc_b[4]  = {(const float*)d_in[5],(const float*)d_in[7],(const float*)d_in[9],(const float*)d_in[11]};
    const float* enc_lat_w = (const float*)d_in[12];
    const float* enc_lat_b = (const float*)d_in[13];
    const float* dec_lin_w = (const float*)d_in[14];
    const float* dec_lin_b = (const float*)d_in[15];
    const float* dec_w[4]  = {(const float*)d_in[16],(const float*)d_in[18],(const float*)d_in[20],(const float*)d_in[22]};
    const float* dec_b[4]  = {(const float*)d_in[17],(const float*)d_in[19],(const float*)d_in[21],(const float*)d_in[23]};
    const float* dec_out_w = (const float*)d_in[24];
    const float* dec_out_b = (const float*)d_in[25];
    const int*   spiral[4] = {(const int*)d_in[26],(const int*)d_in[27],(const int*)d_in[28],(const int*)d_in[29]};

    // down/up arrays: dict order (interleaved per level) vs signature order — detect via sizes.
    const int* dcol[4]; const float* dval[4]; const int* ucol[4]; const float* uval[4];
    bool interleaved = (in_sizes[33] == 3*8192);   // up0_row in dict order
    for (int i = 0; i < 4; i++){
        if (interleaved){
            int b = 30 + 6*i;
            dcol[i] = (const int*)d_in[b+1]; dval[i] = (const float*)d_in[b+2];
            ucol[i] = (const int*)d_in[b+4]; uval[i] = (const float*)d_in[b+5];
        } else {
            dcol[i] = (const int*)d_in[31+3*i]; dval[i] = (const float*)d_in[32+3*i];
            ucol[i] = (const int*)d_in[43+3*i]; uval[i] = (const float*)d_in[44+3*i];
        }
    }

    // ---- workspace layout ----
    char* ws = (char*)d_ws;
    size_t off = 0;
    auto alloc = [&](size_t bytes)->char* {
        char* p = ws + off; off += (bytes + 255) & ~(size_t)255; return p;
    };
    float* encX0 = (float*)alloc((size_t)262144*4);
    float* encP0 = (float*)alloc((size_t)65536*4);
    float* encX1 = (float*)alloc((size_t)131072*4);
    float* encP1 = (float*)alloc((size_t)32768*4);
    float* encX2 = (float*)alloc((size_t)32768*4);
    float* encP2 = (float*)alloc((size_t)8192*4);
    float* encX3 = (float*)alloc((size_t)16384*4);
    float* encP3 = (float*)alloc((size_t)4096*4);
    float* aemb  = (float*)alloc((size_t)4096*4);
    float* pemb  = (float*)alloc((size_t)64*4);
    float* P     = (float*)alloc((size_t)16777216*4);   // 64 MiB f32 ping
    char*  Qraw  =         alloc((size_t)33554432*2);   // 64 MiB pong (f32 or bf16 views)
    float* Qf = (float*)Qraw;
    bf16*  Qb = (bf16*)Qraw;

    // ---- prep ----
    k_audio<<<64,64,0,stream>>>(hs, audio_w, audio_b, aemb);

    // ---- encoder ----
    k_conv<float><<<512,256, 16*28*4, stream>>>(actor, spiral[0], enc_w[0], enc_b[0], encX0, 8192, 8192,13,   3,16,4,  27,  28,16);
    k_pool<float><<<256,256,0,stream>>>(encX0, dcol[0], dval[0], encP0, 65536, 31,5, 2047,11, 8192);
    k_conv<float><<<256,256, 8*292*4, stream>>>(encP0, spiral[1], enc_w[1], enc_b[1], encX1, 2048, 2048,11,  32,32,5, 288, 292, 8);
    k_pool<float><<<128,256,0,stream>>>(encX1, dcol[1], dval[1], encP1, 32768, 63,6, 511,9, 2048);
    k_conv<float><<<64,256, 8*580*4, stream>>>(encP1, spiral[2], enc_w[2], enc_b[2], encX2, 512, 512,9,  64,32,5, 576, 580, 8);
    k_pool<float><<<32,256,0,stream>>>(encX2, dcol[2], dval[2], encP2, 8192, 63,6, 127,7, 512);
    k_conv<float><<<32,256, 4*580*4, stream>>>(encP2, spiral[3], enc_w[3], enc_b[3], encX3, 128, 128,7,  64,64,6, 576, 580, 4);
    k_pool<float><<<16,256,0,stream>>>(encX3, dcol[3], dval[3], encP3, 4096, 127,7, 31,5, 128);
    k_enclat<<<64,256,0,stream>>>(encP3, enc_lat_w, enc_lat_b, pemb);

    // ---- decoder ----
    k_declin<<<dim3(16,64),256,0,stream>>>(aemb, pemb, dec_lin_w, dec_lin_b, P);  // [64,32,128]

    k_pool<float><<<4096,256,0,stream>>>(P, ucol[3], uval[3], Qf, 1048576, 127,7, 127,7, 32);           // ->[64,128,128]
    k_conv<float><<<2048,256, 4*1156*4, stream>>>(Qf, spiral[3], dec_w[0], dec_b[0], P, 8192, 128,7, 128,64,6, 1152,1156, 4);

    k_pool<float><<<16384,256,0,stream>>>(P, ucol[2], uval[2], Qf, 4194304, 127,7, 511,9, 128);         // ->[64,512,128]
    k_conv<float><<<4096,256, 8*1156*4, stream>>>(Qf, spiral[2], dec_w[1], dec_b[1], P, 32768, 512,9, 128,32,5, 1152,1156, 8);

    k_pool<float><<<32768,256,0,stream>>>(P, ucol[1], uval[1], Qf, 8388608, 63,6, 2047,11, 512);        // ->[64,2048,64]
    k_conv<float><<<16384,256, 8*580*4, stream>>>(Qf, spiral[1], dec_w[2], dec_b[2], P, 131072, 2048,11, 64,32,5, 576,580, 8);

    k_pool<bf16><<<131072,256,0,stream>>>(P, ucol[0], uval[0], Qb, 33554432, 63,6, 8191,13, 2048);      // ->[64,8192,64] bf16
    k_conv<bf16><<<32768,256, 16*580*4, stream>>>(Qb, spiral[0], dec_w[3], dec_b[3], P, 524288, 8192,13, 64,16,4, 576,580, 16);

    k_outconv<<<2048,256,0,stream>>>(P, spiral[0], dec_out_w, dec_out_b, actor, (float*)d_out, 524288, 13, 32);
}

// Round 5
// 1180.266 us; speedup vs baseline: 3.9104x; 3.9104x over previous
//
#include <hip/hip_runtime.h>
#include <hip/hip_bf16.h>

typedef __hip_bfloat16 bf16;
typedef __attribute__((ext_vector_type(8))) short short8v;
typedef __attribute__((ext_vector_type(4))) float f32x4;

__device__ __forceinline__ float tof(float v){ return v; }
__device__ __forceinline__ float tof(bf16 v){ return __bfloat162float(v); }
__device__ __forceinline__ void sto(float* p, float v){ *p = v; }
__device__ __forceinline__ void sto(bf16* p, float v){ *p = __float2bfloat16(v); }
__device__ __forceinline__ short f2bs(float f){ bf16 h = __float2bfloat16(f); return *(short*)&h; }
__device__ __forceinline__ float bs2f(short s){ bf16 h = *(bf16*)&s; return tof(h); }

__device__ __forceinline__ float4 ld4f(const float* p){ return *(const float4*)p; }
__device__ __forceinline__ float4 ld4f(const bf16* p){
    float4 r; r.x=tof(p[0]); r.y=tof(p[1]); r.z=tof(p[2]); r.w=tof(p[3]); return r;
}
__device__ __forceinline__ void sto4(float* p, float4 v){ *(float4*)p = v; }
__device__ __forceinline__ void sto4(bf16* p, float4 v){
    short4 s; s.x=f2bs(v.x); s.y=f2bs(v.y); s.z=f2bs(v.z); s.w=f2bs(v.w);
    *(short4*)p = s;
}

// ---------- audio embedding ----------
__global__ __launch_bounds__(64) void k_audio(const float* __restrict__ hs,
    const float* __restrict__ w, const float* __restrict__ b, float* __restrict__ out)
{
    int t = blockIdx.x, l = threadIdx.x;
    float acc = b[l];
    const float* h = hs + t*768;
    #pragma unroll 4
    for (int k = 0; k < 768; k++) acc += h[k] * w[k*64 + l];
    out[t*64 + l] = acc;
}

// ---------- enc_lat ----------
__global__ __launch_bounds__(256) void k_enclat(const float* __restrict__ flat,
    const float* __restrict__ w, const float* __restrict__ b, float* __restrict__ out)
{
    __shared__ float red[256];
    int l = blockIdx.x, tid = threadIdx.x;
    float acc = 0.f;
    for (int k = tid; k < 4096; k += 256) acc += flat[k] * w[k*64 + l];
    red[tid] = acc; __syncthreads();
    for (int s = 128; s > 0; s >>= 1){ if (tid < s) red[tid] += red[tid+s]; __syncthreads(); }
    if (tid == 0) out[l] = red[0] + b[l];
}

// ---------- dec_lin fused with latent concat ----------
__global__ __launch_bounds__(256) void k_declin(const float* __restrict__ ae,
    const float* __restrict__ pe, const float* __restrict__ w, const float* __restrict__ b,
    float* __restrict__ out)
{
    int n = blockIdx.x*256 + threadIdx.x;
    int t = blockIdx.y;
    float acc = b[n];
    const float* a = ae + t*64;
    #pragma unroll 8
    for (int k = 0; k < 64; k++) acc += a[k]  * w[k*4096 + n];
    #pragma unroll 8
    for (int k = 0; k < 64; k++) acc += pe[k] * w[(64+k)*4096 + n];
    out[(size_t)t*4096 + n] = acc;
}

// ---------- weight transpose+convert with hi/lo split ----------
// wt_hi[n*K+k] = bf16(w[k*N+n]); wt_lo = bf16(w - hi)
__global__ __launch_bounds__(256) void k_wtr(const float* __restrict__ w,
    short* __restrict__ wth, short* __restrict__ wtl, int K, int N)
{
    int i = blockIdx.x*256 + threadIdx.x;
    if (i >= K*N) return;
    int n = i / K, k = i - n*K;
    float v = w[(size_t)k*N + n];
    short h = f2bs(v);
    wth[i] = h;
    wtl[i] = f2bs(v - bs2f(h));
}

// ---------- 3-tap pool, 4 channels/thread ----------
template<typename TOUT>
__global__ __launch_bounds__(256) void k_pool4(const float* __restrict__ xin,
    const int* __restrict__ col, const float* __restrict__ val, TOUT* __restrict__ out,
    int total4, int c4mask, int cs, int vomask, int vos, int Vi)
{
    int i = blockIdx.x*256 + threadIdx.x;
    if (i >= total4) return;
    int c4 = i & c4mask;
    int rv = i >> cs;
    int r  = rv & vomask;
    int t  = rv >> vos;
    int C  = (c4mask + 1) << 2;
    const float* xt = xin + (size_t)t * Vi * C;
    int r3 = 3*r;
    int j0 = col[r3], j1 = col[r3+1], j2 = col[r3+2];
    float v0 = val[r3], v1 = val[r3+1], v2 = val[r3+2];
    int c = c4 << 2;
    float4 a = *(const float4*)&xt[(size_t)j0*C + c];
    float4 b = *(const float4*)&xt[(size_t)j1*C + c];
    float4 d = *(const float4*)&xt[(size_t)j2*C + c];
    float4 o;
    o.x = v0*a.x + v1*b.x + v2*d.x;
    o.y = v0*a.y + v1*b.y + v2*d.y;
    o.z = v0*a.z + v1*b.z + v2*d.z;
    o.w = v0*a.w + v1*b.w + v2*d.w;
    sto4(&out[(size_t)i << 2], o);
}

// ---------- MFMA spiral conv + ELU, split-precision ----------
// C[m][n] = elu(bias[n] + sum_k A[m][k] * W[k][n]), A gathered via spiral.
// hi/lo bf16 split: A≈ah+al, W≈wh+wl; acc += ah*wh + ah*wl + (ASPLIT? al*wh).
// Block: 256 threads = 4 waves; M-tile 64, full N, K-tile 64.
template<typename TIN, int N, typename TOUT, bool ASPLIT>
__global__ __launch_bounds__(256) void k_conv_mfma(const TIN* __restrict__ xin,
    const int* __restrict__ spiral, const short* __restrict__ wth, const short* __restrict__ wtl,
    const float* __restrict__ bias, TOUT* __restrict__ out,
    int vshift, int cshift, int K)
{
    __shared__ short lds_ah[64*72];
    __shared__ short lds_al[ASPLIT ? 64*72 : 4];
    __shared__ short lds_bh[N*72];
    __shared__ short lds_bl[N*72];
    const int tid = threadIdx.x;
    const int mbase = blockIdx.x * 64;
    const int lane = tid & 63;
    const int wv = tid >> 6;
    const int col = lane & 15;
    const int quad = lane >> 4;
    const int m0 = wv * 16;
    const int Cm1 = (1 << cshift) - 1;

    f32x4 acc[N/16];
    #pragma unroll
    for (int f = 0; f < N/16; f++){
        float bv = bias[f*16 + col];
        acc[f] = (f32x4){bv, bv, bv, bv};
    }

    const int ntile = K >> 6;
    for (int kt = 0; kt < ntile; kt++){
        int kt0 = kt << 6;
        // stage A: 64 rows x 16 short4-slots, hi (+lo) planes
        #pragma unroll
        for (int e = tid; e < 1024; e += 256){
            int m = e >> 4, kk = (e & 15) << 2;
            int gm = mbase + m;
            int t = gm >> vshift, v = gm - (t << vshift);
            int k = kt0 + kk;
            int s = k >> cshift, c = k & Cm1;
            int j = spiral[v*9 + s];
            float4 va = ld4f(&xin[((((size_t)t << vshift) + j) << cshift) + c]);
            short4 hi; hi.x=f2bs(va.x); hi.y=f2bs(va.y); hi.z=f2bs(va.z); hi.w=f2bs(va.w);
            *(short4*)&lds_ah[m*72 + kk] = hi;
            if (ASPLIT){
                short4 lo;
                lo.x=f2bs(va.x - bs2f(hi.x)); lo.y=f2bs(va.y - bs2f(hi.y));
                lo.z=f2bs(va.z - bs2f(hi.z)); lo.w=f2bs(va.w - bs2f(hi.w));
                *(short4*)&lds_al[m*72 + kk] = lo;
            }
        }
        // stage B: N rows x 16 short4-slots, hi+lo planes
        for (int e = tid; e < N*16; e += 256){
            int n = e >> 4, kk = (e & 15) << 2;
            *(short4*)&lds_bh[n*72 + kk] = *(const short4*)&wth[n*K + kt0 + kk];
            *(short4*)&lds_bl[n*72 + kk] = *(const short4*)&wtl[n*K + kt0 + kk];
        }
        __syncthreads();
        #pragma unroll
        for (int ks = 0; ks < 64; ks += 32){
            short8v ah = *(short8v*)&lds_ah[(m0 + col)*72 + ks + quad*8];
            short8v al;
            if (ASPLIT) al = *(short8v*)&lds_al[(m0 + col)*72 + ks + quad*8];
            #pragma unroll
            for (int f = 0; f < N/16; f++){
                short8v bh = *(short8v*)&lds_bh[(f*16 + col)*72 + ks + quad*8];
                short8v bl = *(short8v*)&lds_bl[(f*16 + col)*72 + ks + quad*8];
                acc[f] = __builtin_amdgcn_mfma_f32_16x16x32_bf16(ah, bh, acc[f], 0, 0, 0);
                acc[f] = __builtin_amdgcn_mfma_f32_16x16x32_bf16(ah, bl, acc[f], 0, 0, 0);
                if (ASPLIT)
                    acc[f] = __builtin_amdgcn_mfma_f32_16x16x32_bf16(al, bh, acc[f], 0, 0, 0);
            }
        }
        __syncthreads();
    }
    // epilogue: C/D layout col=lane&15, row=quad*4+reg
    #pragma unroll
    for (int f = 0; f < N/16; f++){
        #pragma unroll
        for (int r = 0; r < 4; r++){
            int row = m0 + quad*4 + r;
            float vv = acc[f][r];
            vv = vv > 0.f ? vv : __expf(vv) - 1.f;
            sto(&out[(size_t)(mbase + row)*N + f*16 + col], vv);
        }
    }
}

// ---------- VALU spiral conv (encoder; tiny) ----------
template<typename TIN>
__global__ __launch_bounds__(256) void k_conv(const TIN* __restrict__ xin,
    const int* __restrict__ spiral, const float* __restrict__ w, const float* __restrict__ bias,
    float* __restrict__ out, int TV, int V, int vshift, int C, int O2, int o2shift,
    int K, int KP, int MT)
{
    extern __shared__ float lds[];
    const int S = 9;
    int tid = threadIdx.x;
    int O = O2 << 1;
    int gmbase = blockIdx.x * MT;

    int total = MT * K;
    for (int e = tid; e < total; e += 256){
        int m = e / K, k = e - m*K;
        int gm = gmbase + m;
        if (gm < TV){
            int t = gm >> vshift, v = gm & (V-1);
            int s = k / C, c = k - s*C;
            int j = spiral[v*S + s];
            lds[m*KP + k] = tof(xin[((size_t)t*V + j)*C + c]);
        }
    }
    __syncthreads();

    int m = tid >> o2shift;
    int o = tid & (O2 - 1);
    int gm = gmbase + m;
    if (gm >= TV) return;
    const float* g  = lds + m*KP;
    const float* wp = w + 2*o;
    float acc0 = bias[2*o];
    float acc1 = bias[2*o+1];
    int K4 = K & ~3;
    for (int k = 0; k < K4; k += 4){
        float4 g4 = *(const float4*)(g + k);
        float2 w0 = *(const float2*)(wp + (size_t)k    *O);
        float2 w1 = *(const float2*)(wp + (size_t)(k+1)*O);
        float2 w2 = *(const float2*)(wp + (size_t)(k+2)*O);
        float2 w3 = *(const float2*)(wp + (size_t)(k+3)*O);
        acc0 += g4.x*w0.x + g4.y*w1.x + g4.z*w2.x + g4.w*w3.x;
        acc1 += g4.x*w0.y + g4.y*w1.y + g4.z*w2.y + g4.w*w3.y;
    }
    for (int k = K4; k < K; k++){
        float gv = g[k];
        acc0 += gv * wp[(size_t)k*O];
        acc1 += gv * wp[(size_t)k*O + 1];
    }
    acc0 = acc0 > 0.f ? acc0 : __expf(acc0) - 1.f;
    acc1 = acc1 > 0.f ? acc1 : __expf(acc1) - 1.f;
    float2 r; r.x = acc0; r.y = acc1;
    *(float2*)(out + (size_t)gm*O + 2*o) = r;
}

// ---------- final conv (O=3, no ELU) + actor residual ----------
template<typename TIN>
__global__ __launch_bounds__(256) void k_outconv(const TIN* __restrict__ xin,
    const int* __restrict__ spiral, const float* __restrict__ w, const float* __restrict__ bias,
    const float* __restrict__ actor, float* __restrict__ out, int TV, int vshift, int C)
{
    int i = blockIdx.x*256 + threadIdx.x;
    if (i >= TV) return;
    int V = 1 << vshift;
    int v = i & (V-1);
    int t = i >> vshift;
    const TIN* xt = xin + (size_t)t * V * C;
    float a0 = bias[0], a1 = bias[1], a2 = bias[2];
    for (int s = 0; s < 9; s++){
        int j = spiral[v*9 + s];
        const TIN* xr = xt + (size_t)j*C;
        const float* wr = w + s*C*3;
        for (int c = 0; c < C; c += 4){
            float4 xv = ld4f(xr + c);
            a0 += xv.x*wr[c*3]   + xv.y*wr[c*3+3] + xv.z*wr[c*3+6] + xv.w*wr[c*3+9];
            a1 += xv.x*wr[c*3+1] + xv.y*wr[c*3+4] + xv.z*wr[c*3+7] + xv.w*wr[c*3+10];
            a2 += xv.x*wr[c*3+2] + xv.y*wr[c*3+5] + xv.z*wr[c*3+8] + xv.w*wr[c*3+11];
        }
    }
    a0 += actor[v*3]; a1 += actor[v*3+1]; a2 += actor[v*3+2];
    out[(size_t)i*3]   = a0;
    out[(size_t)i*3+1] = a1;
    out[(size_t)i*3+2] = a2;
}

extern "C" void kernel_launch(void* const* d_in, const int* in_sizes, int n_in,
                              void* d_out, int out_size, void* d_ws, size_t ws_size,
                              hipStream_t stream)
{
    (void)n_in; (void)out_size; (void)ws_size;
    const float* hs        = (const float*)d_in[0];
    const float* actor     = (const float*)d_in[1];
    const float* audio_w   = (const float*)d_in[2];
    const float* audio_b   = (const float*)d_in[3];
    const float* enc_w[4]  = {(const float*)d_in[4],(const float*)d_in[6],(const float*)d_in[8],(const float*)d_in[10]};
    const float* enc_b[4]  = {(const float*)d_in[5],(const float*)d_in[7],(const float*)d_in[9],(const float*)d_in[11]};
    const float* enc_lat_w = (const float*)d_in[12];
    const float* enc_lat_b = (const float*)d_in[13];
    const float* dec_lin_w = (const float*)d_in[14];
    const float* dec_lin_b = (const float*)d_in[15];
    const float* dec_w[4]  = {(const float*)d_in[16],(const float*)d_in[18],(const float*)d_in[20],(const float*)d_in[22]};
    const float* dec_b[4]  = {(const float*)d_in[17],(const float*)d_in[19],(const float*)d_in[21],(const float*)d_in[23]};
    const float* dec_out_w = (const float*)d_in[24];
    const float* dec_out_b = (const float*)d_in[25];
    const int*   spiral[4] = {(const int*)d_in[26],(const int*)d_in[27],(const int*)d_in[28],(const int*)d_in[29]};

    const int* dcol[4]; const float* dval[4]; const int* ucol[4]; const float* uval[4];
    bool interleaved = (in_sizes[33] == 3*8192);
    for (int i = 0; i < 4; i++){
        if (interleaved){
            int b = 30 + 6*i;
            dcol[i] = (const int*)d_in[b+1]; dval[i] = (const float*)d_in[b+2];
            ucol[i] = (const int*)d_in[b+4]; uval[i] = (const float*)d_in[b+5];
        } else {
            dcol[i] = (const int*)d_in[31+3*i]; dval[i] = (const float*)d_in[32+3*i];
            ucol[i] = (const int*)d_in[43+3*i]; uval[i] = (const float*)d_in[44+3*i];
        }
    }

    // ---- workspace ----
    char* ws = (char*)d_ws;
    size_t off = 0;
    auto alloc = [&](size_t bytes)->char* {
        char* p = ws + off; off += (bytes + 255) & ~(size_t)255; return p;
    };
    float* encX0 = (float*)alloc((size_t)262144*4);
    float* encP0 = (float*)alloc((size_t)65536*4);
    float* encX1 = (float*)alloc((size_t)131072*4);
    float* encP1 = (float*)alloc((size_t)32768*4);
    float* encX2 = (float*)alloc((size_t)32768*4);
    float* encP2 = (float*)alloc((size_t)8192*4);
    float* encX3 = (float*)alloc((size_t)16384*4);
    float* encP3 = (float*)alloc((size_t)4096*4);
    float* aemb  = (float*)alloc((size_t)4096*4);
    float* pemb  = (float*)alloc((size_t)64*4);
    short* wt0h  = (short*)alloc((size_t)147456*2);   // dec0 [128][1152]
    short* wt0l  = (short*)alloc((size_t)147456*2);
    short* wt1h  = (short*)alloc((size_t)73728*2);    // dec1 [64][1152]  (N=64!)
    short* wt1l  = (short*)alloc((size_t)73728*2);
    short* wt2h  = (short*)alloc((size_t)36864*2);    // dec2 [64][576]
    short* wt2l  = (short*)alloc((size_t)36864*2);
    short* wt3h  = (short*)alloc((size_t)18432*2);    // dec3 [32][576]
    short* wt3l  = (short*)alloc((size_t)18432*2);
    float* P     = (float*)alloc((size_t)16777216*4); // 64 MiB ping
    char*  Qraw  =         alloc((size_t)33554432*2); // 64 MiB pong
    float* Qf = (float*)Qraw;
    bf16*  Qb = (bf16*)Qraw;

    // ---- prep ----
    k_audio<<<64,64,0,stream>>>(hs, audio_w, audio_b, aemb);
    k_wtr<<<576,256,0,stream>>>(dec_w[0], wt0h, wt0l, 1152, 128);
    k_wtr<<<288,256,0,stream>>>(dec_w[1], wt1h, wt1l, 1152, 64);
    k_wtr<<<144,256,0,stream>>>(dec_w[2], wt2h, wt2l, 576, 64);
    k_wtr<<<72,256,0,stream>>>(dec_w[3], wt3h, wt3l, 576, 32);

    // ---- encoder (VALU; tiny) ----
    k_conv<float><<<512,256, 16*28*4, stream>>>(actor, spiral[0], enc_w[0], enc_b[0], encX0, 8192, 8192,13,   3,16,4,  27,  28,16);
    k_pool4<float><<<64,256,0,stream>>>(encX0, dcol[0], dval[0], encP0, 16384, 7,3, 2047,11, 8192);
    k_conv<float><<<256,256, 8*292*4, stream>>>(encP0, spiral[1], enc_w[1], enc_b[1], encX1, 2048, 2048,11,  32,32,5, 288, 292, 8);
    k_pool4<float><<<32,256,0,stream>>>(encX1, dcol[1], dval[1], encP1, 8192, 15,4, 511,9, 2048);
    k_conv<float><<<64,256, 8*580*4, stream>>>(encP1, spiral[2], enc_w[2], enc_b[2], encX2, 512, 512,9,  64,32,5, 576, 580, 8);
    k_pool4<float><<<8,256,0,stream>>>(encX2, dcol[2], dval[2], encP2, 2048, 15,4, 127,7, 512);
    k_conv<float><<<32,256, 4*580*4, stream>>>(encP2, spiral[3], enc_w[3], enc_b[3], encX3, 128, 128,7,  64,64,6, 576, 580, 4);
    k_pool4<float><<<4,256,0,stream>>>(encX3, dcol[3], dval[3], encP3, 1024, 31,5, 31,5, 128);
    k_enclat<<<64,256,0,stream>>>(encP3, enc_lat_w, enc_lat_b, pemb);

    // ---- decoder ----
    k_declin<<<dim3(16,64),256,0,stream>>>(aemb, pemb, dec_lin_w, dec_lin_b, P);  // [64,32,128]

    k_pool4<float><<<1024,256,0,stream>>>(P, ucol[3], uval[3], Qf, 262144, 31,5, 127,7, 32);     // ->[64,128,128]
    k_conv_mfma<float,128,float,true><<<128,256,0,stream>>>(Qf, spiral[3], wt0h, wt0l, dec_b[0], P, 7, 7, 1152);   // ->[64,128,128]

    k_pool4<float><<<4096,256,0,stream>>>(P, ucol[2], uval[2], Qf, 1048576, 31,5, 511,9, 128);   // ->[64,512,128]
    k_conv_mfma<float,64,float,true><<<512,256,0,stream>>>(Qf, spiral[2], wt1h, wt1l, dec_b[1], P, 9, 7, 1152);    // ->[64,512,64]  N=64!

    k_pool4<float><<<8192,256,0,stream>>>(P, ucol[1], uval[1], Qf, 2097152, 15,4, 2047,11, 512); // ->[64,2048,64]
    k_conv_mfma<float,64,float,true><<<2048,256,0,stream>>>(Qf, spiral[1], wt2h, wt2l, dec_b[2], P, 11, 6, 576);   // ->[64,2048,64]

    k_pool4<bf16><<<32768,256,0,stream>>>(P, ucol[0], uval[0], Qb, 8388608, 15,4, 8191,13, 2048);// ->[64,8192,64] bf16
    k_conv_mfma<bf16,32,float,false><<<8192,256,0,stream>>>(Qb, spiral[0], wt3h, wt3l, dec_b[3], P, 13, 6, 576);   // ->[64,8192,32] f32

    k_outconv<float><<<2048,256,0,stream>>>(P, spiral[0], dec_out_w, dec_out_b, actor, (float*)d_out, 524288, 13, 32);
}

// Round 6
// 922.112 us; speedup vs baseline: 5.0052x; 1.2800x over previous
//
#include <hip/hip_runtime.h>
#include <hip/hip_bf16.h>

typedef __hip_bfloat16 bf16;
typedef __attribute__((ext_vector_type(8))) short short8v;
typedef __attribute__((ext_vector_type(4))) float f32x4;

__device__ __forceinline__ float tof(float v){ return v; }
__device__ __forceinline__ float tof(bf16 v){ return __bfloat162float(v); }
__device__ __forceinline__ void sto(float* p, float v){ *p = v; }
__device__ __forceinline__ void sto(bf16* p, float v){ *p = __float2bfloat16(v); }
__device__ __forceinline__ short f2bs(float f){ bf16 h = __float2bfloat16(f); return *(short*)&h; }
__device__ __forceinline__ float bs2f(short s){ bf16 h = *(bf16*)&s; return tof(h); }

__device__ __forceinline__ float4 ld4f(const float* p){ return *(const float4*)p; }
__device__ __forceinline__ float4 ld4f(const bf16* p){
    float4 r; r.x=tof(p[0]); r.y=tof(p[1]); r.z=tof(p[2]); r.w=tof(p[3]); return r;
}
__device__ __forceinline__ short4 ld4bf(const bf16* p){ return *(const short4*)p; }
__device__ __forceinline__ void sto4(float* p, float4 v){ *(float4*)p = v; }
__device__ __forceinline__ void sto4(bf16* p, float4 v){
    short4 s; s.x=f2bs(v.x); s.y=f2bs(v.y); s.z=f2bs(v.z); s.w=f2bs(v.w);
    *(short4*)p = s;
}

// XCD-aware swizzle for 64-frame (t) problems: grid = 64 << bs blocks,
// block b -> xcd = b&7 (round-robin dispatch), per-XCD t-range of 8 frames,
// consecutive per-XCD blocks share t => per-XCD L2 working set = 1 t-slab.
__device__ __forceinline__ void swz_t(int b, int bs, int& t, int& rem){
    int x = b & 7, k = b >> 3;
    t = x*8 + (k >> bs);
    rem = k & ((1 << bs) - 1);
}

// ---------- audio embedding ----------
__global__ __launch_bounds__(64) void k_audio(const float* __restrict__ hs,
    const float* __restrict__ w, const float* __restrict__ b, float* __restrict__ out)
{
    int t = blockIdx.x, l = threadIdx.x;
    float acc = b[l];
    const float* h = hs + t*768;
    #pragma unroll 4
    for (int k = 0; k < 768; k++) acc += h[k] * w[k*64 + l];
    out[t*64 + l] = acc;
}

// ---------- enc_lat ----------
__global__ __launch_bounds__(256) void k_enclat(const float* __restrict__ flat,
    const float* __restrict__ w, const float* __restrict__ b, float* __restrict__ out)
{
    __shared__ float red[256];
    int l = blockIdx.x, tid = threadIdx.x;
    float acc = 0.f;
    for (int k = tid; k < 4096; k += 256) acc += flat[k] * w[k*64 + l];
    red[tid] = acc; __syncthreads();
    for (int s = 128; s > 0; s >>= 1){ if (tid < s) red[tid] += red[tid+s]; __syncthreads(); }
    if (tid == 0) out[l] = red[0] + b[l];
}

// ---------- dec_lin fused with latent concat ----------
__global__ __launch_bounds__(256) void k_declin(const float* __restrict__ ae,
    const float* __restrict__ pe, const float* __restrict__ w, const float* __restrict__ b,
    float* __restrict__ out)
{
    int n = blockIdx.x*256 + threadIdx.x;
    int t = blockIdx.y;
    float acc = b[n];
    const float* a = ae + t*64;
    #pragma unroll 8
    for (int k = 0; k < 64; k++) acc += a[k]  * w[k*4096 + n];
    #pragma unroll 8
    for (int k = 0; k < 64; k++) acc += pe[k] * w[(64+k)*4096 + n];
    out[(size_t)t*4096 + n] = acc;
}

// ---------- weight transpose+convert with hi/lo split ----------
__global__ __launch_bounds__(256) void k_wtr(const float* __restrict__ w,
    short* __restrict__ wth, short* __restrict__ wtl, int K, int N)
{
    int i = blockIdx.x*256 + threadIdx.x;
    if (i >= K*N) return;
    int n = i / K, k = i - n*K;
    float v = w[(size_t)k*N + n];
    short h = f2bs(v);
    wth[i] = h;
    wtl[i] = f2bs(v - bs2f(h));
}

// ---------- 3-tap pool, 4 channels/thread; bs>=0 -> XCD swizzle, ept4 = total4/64 ----------
template<typename TOUT>
__global__ __launch_bounds__(256) void k_pool4(const float* __restrict__ xin,
    const int* __restrict__ col, const float* __restrict__ val, TOUT* __restrict__ out,
    int total4, int c4mask, int cs, int vomask, int vos, int Vi, int bs, int ept4)
{
    int i;
    int c4, r, t;
    if (bs >= 0){
        int rem; swz_t(blockIdx.x, bs, t, rem);
        int il = rem*256 + threadIdx.x;
        i = t*ept4 + il;
        c4 = il & c4mask;
        r  = (il >> cs) & vomask;
    } else {
        i = blockIdx.x*256 + threadIdx.x;
        if (i >= total4) return;
        c4 = i & c4mask;
        int rv = i >> cs;
        r  = rv & vomask;
        t  = rv >> vos;
    }
    int C  = (c4mask + 1) << 2;
    const float* xt = xin + (size_t)t * Vi * C;
    int r3 = 3*r;
    int j0 = col[r3], j1 = col[r3+1], j2 = col[r3+2];
    float v0 = val[r3], v1 = val[r3+1], v2 = val[r3+2];
    int c = c4 << 2;
    float4 a = *(const float4*)&xt[(size_t)j0*C + c];
    float4 b = *(const float4*)&xt[(size_t)j1*C + c];
    float4 d = *(const float4*)&xt[(size_t)j2*C + c];
    float4 o;
    o.x = v0*a.x + v1*b.x + v2*d.x;
    o.y = v0*a.y + v1*b.y + v2*d.y;
    o.z = v0*a.z + v1*b.z + v2*d.z;
    o.w = v0*a.w + v1*b.w + v2*d.w;
    sto4(&out[(size_t)i << 2], o);
}

// ---------- MFMA spiral conv + ELU, split-precision, XCD-swizzled ----------
// grid = 64 << swzshift blocks; tiles-per-t = 1<<swzshift (= V/64).
template<typename TIN, int N, typename TOUT, bool ASPLIT>
__global__ __launch_bounds__(256) void k_conv_mfma(const TIN* __restrict__ xin,
    const int* __restrict__ spiral, const short* __restrict__ wth, const short* __restrict__ wtl,
    const float* __restrict__ bias, TOUT* __restrict__ out,
    int vshift, int cshift, int K, int swzshift)
{
    __shared__ short lds_ah[64*72];
    __shared__ short lds_al[ASPLIT ? 64*72 : 4];
    __shared__ short lds_bh[N*72];
    __shared__ short lds_bl[N*72];
    const int tid = threadIdx.x;
    int tswz, mt; swz_t(blockIdx.x, swzshift, tswz, mt);
    const int mbase = (tswz << vshift) + mt*64;
    const int lane = tid & 63;
    const int wv = tid >> 6;
    const int col = lane & 15;
    const int quad = lane >> 4;
    const int m0 = wv * 16;
    const int Cm1 = (1 << cshift) - 1;

    f32x4 acc[N/16];
    #pragma unroll
    for (int f = 0; f < N/16; f++){
        float bv = bias[f*16 + col];
        acc[f] = (f32x4){bv, bv, bv, bv};
    }

    const int ntile = K >> 6;
    for (int kt = 0; kt < ntile; kt++){
        int kt0 = kt << 6;
        // stage A: 64 rows x 16 short4-slots
        #pragma unroll
        for (int e = tid; e < 1024; e += 256){
            int m = e >> 4, kk = (e & 15) << 2;
            int gm = mbase + m;
            int t = gm >> vshift, v = gm - (t << vshift);
            int k = kt0 + kk;
            int s = k >> cshift, c = k & Cm1;
            int j = spiral[v*9 + s];
            const TIN* src = &xin[((((size_t)t << vshift) + j) << cshift) + c];
            if (ASPLIT){
                float4 va = ld4f(src);
                short4 hi; hi.x=f2bs(va.x); hi.y=f2bs(va.y); hi.z=f2bs(va.z); hi.w=f2bs(va.w);
                *(short4*)&lds_ah[m*72 + kk] = hi;
                short4 lo;
                lo.x=f2bs(va.x - bs2f(hi.x)); lo.y=f2bs(va.y - bs2f(hi.y));
                lo.z=f2bs(va.z - bs2f(hi.z)); lo.w=f2bs(va.w - bs2f(hi.w));
                *(short4*)&lds_al[m*72 + kk] = lo;
            } else {
                *(short4*)&lds_ah[m*72 + kk] = ld4bf((const bf16*)src);
            }
        }
        // stage B
        for (int e = tid; e < N*16; e += 256){
            int n = e >> 4, kk = (e & 15) << 2;
            *(short4*)&lds_bh[n*72 + kk] = *(const short4*)&wth[n*K + kt0 + kk];
            *(short4*)&lds_bl[n*72 + kk] = *(const short4*)&wtl[n*K + kt0 + kk];
        }
        __syncthreads();
        #pragma unroll
        for (int ks = 0; ks < 64; ks += 32){
            short8v ah = *(short8v*)&lds_ah[(m0 + col)*72 + ks + quad*8];
            short8v al;
            if (ASPLIT) al = *(short8v*)&lds_al[(m0 + col)*72 + ks + quad*8];
            #pragma unroll
            for (int f = 0; f < N/16; f++){
                short8v bh = *(short8v*)&lds_bh[(f*16 + col)*72 + ks + quad*8];
                short8v bl = *(short8v*)&lds_bl[(f*16 + col)*72 + ks + quad*8];
                acc[f] = __builtin_amdgcn_mfma_f32_16x16x32_bf16(ah, bh, acc[f], 0, 0, 0);
                acc[f] = __builtin_amdgcn_mfma_f32_16x16x32_bf16(ah, bl, acc[f], 0, 0, 0);
                if (ASPLIT)
                    acc[f] = __builtin_amdgcn_mfma_f32_16x16x32_bf16(al, bh, acc[f], 0, 0, 0);
            }
        }
        __syncthreads();
    }
    // epilogue: C/D layout col=lane&15, row=quad*4+reg
    #pragma unroll
    for (int f = 0; f < N/16; f++){
        #pragma unroll
        for (int r = 0; r < 4; r++){
            int row = m0 + quad*4 + r;
            float vv = acc[f][r];
            vv = vv > 0.f ? vv : __expf(vv) - 1.f;
            sto(&out[(size_t)(mbase + row)*N + f*16 + col], vv);
        }
    }
}

// ---------- VALU spiral conv (encoder; tiny) ----------
template<typename TIN>
__global__ __launch_bounds__(256) void k_conv(const TIN* __restrict__ xin,
    const int* __restrict__ spiral, const float* __restrict__ w, const float* __restrict__ bias,
    float* __restrict__ out, int TV, int V, int vshift, int C, int O2, int o2shift,
    int K, int KP, int MT)
{
    extern __shared__ float lds[];
    const int S = 9;
    int tid = threadIdx.x;
    int O = O2 << 1;
    int gmbase = blockIdx.x * MT;

    int total = MT * K;
    for (int e = tid; e < total; e += 256){
        int m = e / K, k = e - m*K;
        int gm = gmbase + m;
        if (gm < TV){
            int t = gm >> vshift, v = gm & (V-1);
            int s = k / C, c = k - s*C;
            int j = spiral[v*S + s];
            lds[m*KP + k] = tof(xin[((size_t)t*V + j)*C + c]);
        }
    }
    __syncthreads();

    int m = tid >> o2shift;
    int o = tid & (O2 - 1);
    int gm = gmbase + m;
    if (gm >= TV) return;
    const float* g  = lds + m*KP;
    const float* wp = w + 2*o;
    float acc0 = bias[2*o];
    float acc1 = bias[2*o+1];
    int K4 = K & ~3;
    for (int k = 0; k < K4; k += 4){
        float4 g4 = *(const float4*)(g + k);
        float2 w0 = *(const float2*)(wp + (size_t)k    *O);
        float2 w1 = *(const float2*)(wp + (size_t)(k+1)*O);
        float2 w2 = *(const float2*)(wp + (size_t)(k+2)*O);
        float2 w3 = *(const float2*)(wp + (size_t)(k+3)*O);
        acc0 += g4.x*w0.x + g4.y*w1.x + g4.z*w2.x + g4.w*w3.x;
        acc1 += g4.x*w0.y + g4.y*w1.y + g4.z*w2.y + g4.w*w3.y;
    }
    for (int k = K4; k < K; k++){
        float gv = g[k];
        acc0 += gv * wp[(size_t)k*O];
        acc1 += gv * wp[(size_t)k*O + 1];
    }
    acc0 = acc0 > 0.f ? acc0 : __expf(acc0) - 1.f;
    acc1 = acc1 > 0.f ? acc1 : __expf(acc1) - 1.f;
    float2 r; r.x = acc0; r.y = acc1;
    *(float2*)(out + (size_t)gm*O + 2*o) = r;
}

// ---------- final conv (O=3, no ELU) + actor residual; bf16 input, XCD-swizzled ----------
__global__ __launch_bounds__(256) void k_outconv(const bf16* __restrict__ xin,
    const int* __restrict__ spiral, const float* __restrict__ w, const float* __restrict__ bias,
    const float* __restrict__ actor, float* __restrict__ out, int vshift, int C, int bs)
{
    int t, rem; swz_t(blockIdx.x, bs, t, rem);
    int v = rem*256 + threadIdx.x;
    int V = 1 << vshift;
    size_t i = ((size_t)t << vshift) + v;
    const bf16* xt = xin + ((size_t)t * V) * C;
    float a0 = bias[0], a1 = bias[1], a2 = bias[2];
    for (int s = 0; s < 9; s++){
        int j = spiral[v*9 + s];
        const bf16* xr = xt + (size_t)j*C;
        const float* wr = w + s*C*3;
        for (int c = 0; c < C; c += 4){
            float4 xv = ld4f(xr + c);
            a0 += xv.x*wr[c*3]   + xv.y*wr[c*3+3] + xv.z*wr[c*3+6] + xv.w*wr[c*3+9];
            a1 += xv.x*wr[c*3+1] + xv.y*wr[c*3+4] + xv.z*wr[c*3+7] + xv.w*wr[c*3+10];
            a2 += xv.x*wr[c*3+2] + xv.y*wr[c*3+5] + xv.z*wr[c*3+8] + xv.w*wr[c*3+11];
        }
    }
    a0 += actor[v*3]; a1 += actor[v*3+1]; a2 += actor[v*3+2];
    out[i*3]   = a0;
    out[i*3+1] = a1;
    out[i*3+2] = a2;
}

extern "C" void kernel_launch(void* const* d_in, const int* in_sizes, int n_in,
                              void* d_out, int out_size, void* d_ws, size_t ws_size,
                              hipStream_t stream)
{
    (void)n_in; (void)out_size; (void)ws_size;
    const float* hs        = (const float*)d_in[0];
    const float* actor     = (const float*)d_in[1];
    const float* audio_w   = (const float*)d_in[2];
    const float* audio_b   = (const float*)d_in[3];
    const float* enc_w[4]  = {(const float*)d_in[4],(const float*)d_in[6],(const float*)d_in[8],(const float*)d_in[10]};
    const float* enc_b[4]  = {(const float*)d_in[5],(const float*)d_in[7],(const float*)d_in[9],(const float*)d_in[11]};
    const float* enc_lat_w = (const float*)d_in[12];
    const float* enc_lat_b = (const float*)d_in[13];
    const float* dec_lin_w = (const float*)d_in[14];
    const float* dec_lin_b = (const float*)d_in[15];
    const float* dec_w[4]  = {(const float*)d_in[16],(const float*)d_in[18],(const float*)d_in[20],(const float*)d_in[22]};
    const float* dec_b[4]  = {(const float*)d_in[17],(const float*)d_in[19],(const float*)d_in[21],(const float*)d_in[23]};
    const float* dec_out_w = (const float*)d_in[24];
    const float* dec_out_b = (const float*)d_in[25];
    const int*   spiral[4] = {(const int*)d_in[26],(const int*)d_in[27],(const int*)d_in[28],(const int*)d_in[29]};

    const int* dcol[4]; const float* dval[4]; const int* ucol[4]; const float* uval[4];
    bool interleaved = (in_sizes[33] == 3*8192);
    for (int i = 0; i < 4; i++){
        if (interleaved){
            int b = 30 + 6*i;
            dcol[i] = (const int*)d_in[b+1]; dval[i] = (const float*)d_in[b+2];
            ucol[i] = (const int*)d_in[b+4]; uval[i] = (const float*)d_in[b+5];
        } else {
            dcol[i] = (const int*)d_in[31+3*i]; dval[i] = (const float*)d_in[32+3*i];
            ucol[i] = (const int*)d_in[43+3*i]; uval[i] = (const float*)d_in[44+3*i];
        }
    }

    // ---- workspace ----
    char* ws = (char*)d_ws;
    size_t off = 0;
    auto alloc = [&](size_t bytes)->char* {
        char* p = ws + off; off += (bytes + 255) & ~(size_t)255; return p;
    };
    float* encX0 = (float*)alloc((size_t)262144*4);
    float* encP0 = (float*)alloc((size_t)65536*4);
    float* encX1 = (float*)alloc((size_t)131072*4);
    float* encP1 = (float*)alloc((size_t)32768*4);
    float* encX2 = (float*)alloc((size_t)32768*4);
    float* encP2 = (float*)alloc((size_t)8192*4);
    float* encX3 = (float*)alloc((size_t)16384*4);
    float* encP3 = (float*)alloc((size_t)4096*4);
    float* aemb  = (float*)alloc((size_t)4096*4);
    float* pemb  = (float*)alloc((size_t)64*4);
    short* wt0h  = (short*)alloc((size_t)147456*2);   // dec0 [128][1152]
    short* wt0l  = (short*)alloc((size_t)147456*2);
    short* wt1h  = (short*)alloc((size_t)73728*2);    // dec1 [64][1152]
    short* wt1l  = (short*)alloc((size_t)73728*2);
    short* wt2h  = (short*)alloc((size_t)36864*2);    // dec2 [64][576]
    short* wt2l  = (short*)alloc((size_t)36864*2);
    short* wt3h  = (short*)alloc((size_t)18432*2);    // dec3 [32][576]
    short* wt3l  = (short*)alloc((size_t)18432*2);
    float* P     = (float*)alloc((size_t)16777216*4); // 64 MiB ping
    char*  Qraw  =         alloc((size_t)33554432*2); // 64 MiB pong
    float* Qf = (float*)Qraw;
    bf16*  Qb = (bf16*)Qraw;

    // ---- prep ----
    k_audio<<<64,64,0,stream>>>(hs, audio_w, audio_b, aemb);
    k_wtr<<<576,256,0,stream>>>(dec_w[0], wt0h, wt0l, 1152, 128);
    k_wtr<<<288,256,0,stream>>>(dec_w[1], wt1h, wt1l, 1152, 64);
    k_wtr<<<144,256,0,stream>>>(dec_w[2], wt2h, wt2l, 576, 64);
    k_wtr<<<72,256,0,stream>>>(dec_w[3], wt3h, wt3l, 576, 32);

    // ---- encoder (VALU; tiny, B=1 so no t-swizzle) ----
    k_conv<float><<<512,256, 16*28*4, stream>>>(actor, spiral[0], enc_w[0], enc_b[0], encX0, 8192, 8192,13,   3,16,4,  27,  28,16);
    k_pool4<float><<<64,256,0,stream>>>(encX0, dcol[0], dval[0], encP0, 16384, 7,3, 2047,11, 8192, -1,0);
    k_conv<float><<<256,256, 8*292*4, stream>>>(encP0, spiral[1], enc_w[1], enc_b[1], encX1, 2048, 2048,11,  32,32,5, 288, 292, 8);
    k_pool4<float><<<32,256,0,stream>>>(encX1, dcol[1], dval[1], encP1, 8192, 15,4, 511,9, 2048, -1,0);
    k_conv<float><<<64,256, 8*580*4, stream>>>(encP1, spiral[2], enc_w[2], enc_b[2], encX2, 512, 512,9,  64,32,5, 576, 580, 8);
    k_pool4<float><<<8,256,0,stream>>>(encX2, dcol[2], dval[2], encP2, 2048, 15,4, 127,7, 512, -1,0);
    k_conv<float><<<32,256, 4*580*4, stream>>>(encP2, spiral[3], enc_w[3], enc_b[3], encX3, 128, 128,7,  64,64,6, 576, 580, 4);
    k_pool4<float><<<4,256,0,stream>>>(encX3, dcol[3], dval[3], encP3, 1024, 31,5, 31,5, 128, -1,0);
    k_enclat<<<64,256,0,stream>>>(encP3, enc_lat_w, enc_lat_b, pemb);

    // ---- decoder (all grids = 64<<bs blocks; XCD t-swizzled) ----
    k_declin<<<dim3(16,64),256,0,stream>>>(aemb, pemb, dec_lin_w, dec_lin_b, P);  // [64,32,128]

    k_pool4<float><<<1024,256,0,stream>>>(P, ucol[3], uval[3], Qf, 262144, 31,5, 127,7, 32, 4, 4096);     // ->[64,128,128]
    k_conv_mfma<float,128,float,true><<<128,256,0,stream>>>(Qf, spiral[3], wt0h, wt0l, dec_b[0], P, 7, 7, 1152, 1);   // ->[64,128,128]

    k_pool4<float><<<4096,256,0,stream>>>(P, ucol[2], uval[2], Qf, 1048576, 31,5, 511,9, 128, 6, 16384);  // ->[64,512,128]
    k_conv_mfma<float,64,float,true><<<512,256,0,stream>>>(Qf, spiral[2], wt1h, wt1l, dec_b[1], P, 9, 7, 1152, 3);    // ->[64,512,64]

    k_pool4<float><<<8192,256,0,stream>>>(P, ucol[1], uval[1], Qf, 2097152, 15,4, 2047,11, 512, 7, 32768); // ->[64,2048,64]
    k_conv_mfma<float,64,float,true><<<2048,256,0,stream>>>(Qf, spiral[1], wt2h, wt2l, dec_b[2], P, 11, 6, 576, 5);   // ->[64,2048,64]

    k_pool4<bf16><<<32768,256,0,stream>>>(P, ucol[0], uval[0], Qb, 8388608, 15,4, 8191,13, 2048, 9, 131072); // ->[64,8192,64] bf16
    k_conv_mfma<bf16,32,bf16,false><<<8192,256,0,stream>>>(Qb, spiral[0], wt3h, wt3l, dec_b[3], (bf16*)P, 13, 6, 576, 7); // ->[64,8192,32] bf16

    k_outconv<<<2048,256,0,stream>>>((const bf16*)P, spiral[0], dec_out_w, dec_out_b, actor, (float*)d_out, 13, 32, 5);
}

// Round 7
// 671.319 us; speedup vs baseline: 6.8751x; 1.3736x over previous
//
#include <hip/hip_runtime.h>
#include <hip/hip_bf16.h>

typedef __hip_bfloat16 bf16;
typedef __attribute__((ext_vector_type(8))) short short8v;
typedef __attribute__((ext_vector_type(4))) float f32x4;

__device__ __forceinline__ float tof(float v){ return v; }
__device__ __forceinline__ float tof(bf16 v){ return __bfloat162float(v); }
__device__ __forceinline__ void sto(float* p, float v){ *p = v; }
__device__ __forceinline__ void sto(bf16* p, float v){ *p = __float2bfloat16(v); }
__device__ __forceinline__ short f2bs(float f){ bf16 h = __float2bfloat16(f); return *(short*)&h; }
__device__ __forceinline__ float bs2f(short s){ bf16 h = *(bf16*)&s; return tof(h); }
__device__ __forceinline__ float bsu2f(short s){
    return __uint_as_float(((unsigned)(unsigned short)s) << 16);
}

__device__ __forceinline__ float4 ld4f(const float* p){ return *(const float4*)p; }
__device__ __forceinline__ void sto4(float* p, float4 v){ *(float4*)p = v; }
__device__ __forceinline__ void sto4(bf16* p, float4 v){
    short4 s; s.x=f2bs(v.x); s.y=f2bs(v.y); s.z=f2bs(v.z); s.w=f2bs(v.w);
    *(short4*)p = s;
}

// XCD-aware swizzle for 64-frame (t) problems: grid = 64 << bs blocks,
// block b -> xcd = b&7 (round-robin dispatch), per-XCD t-range of 8 frames.
__device__ __forceinline__ void swz_t(int b, int bs, int& t, int& rem){
    int x = b & 7, k = b >> 3;
    t = x*8 + (k >> bs);
    rem = k & ((1 << bs) - 1);
}

// ---------- audio embedding ----------
__global__ __launch_bounds__(64) void k_audio(const float* __restrict__ hs,
    const float* __restrict__ w, const float* __restrict__ b, float* __restrict__ out)
{
    int t = blockIdx.x, l = threadIdx.x;
    float acc = b[l];
    const float* h = hs + t*768;
    #pragma unroll 4
    for (int k = 0; k < 768; k++) acc += h[k] * w[k*64 + l];
    out[t*64 + l] = acc;
}

// ---------- enc_lat ----------
__global__ __launch_bounds__(256) void k_enclat(const float* __restrict__ flat,
    const float* __restrict__ w, const float* __restrict__ b, float* __restrict__ out)
{
    __shared__ float red[256];
    int l = blockIdx.x, tid = threadIdx.x;
    float acc = 0.f;
    for (int k = tid; k < 4096; k += 256) acc += flat[k] * w[k*64 + l];
    red[tid] = acc; __syncthreads();
    for (int s = 128; s > 0; s >>= 1){ if (tid < s) red[tid] += red[tid+s]; __syncthreads(); }
    if (tid == 0) out[l] = red[0] + b[l];
}

// ---------- dec_lin fused with latent concat ----------
__global__ __launch_bounds__(256) void k_declin(const float* __restrict__ ae,
    const float* __restrict__ pe, const float* __restrict__ w, const float* __restrict__ b,
    float* __restrict__ out)
{
    int n = blockIdx.x*256 + threadIdx.x;
    int t = blockIdx.y;
    float acc = b[n];
    const float* a = ae + t*64;
    #pragma unroll 8
    for (int k = 0; k < 64; k++) acc += a[k]  * w[k*4096 + n];
    #pragma unroll 8
    for (int k = 0; k < 64; k++) acc += pe[k] * w[(64+k)*4096 + n];
    out[(size_t)t*4096 + n] = acc;
}

// ---------- weight transpose+convert with hi/lo split ----------
__global__ __launch_bounds__(256) void k_wtr(const float* __restrict__ w,
    short* __restrict__ wth, short* __restrict__ wtl, int K, int N)
{
    int i = blockIdx.x*256 + threadIdx.x;
    if (i >= K*N) return;
    int n = i / K, k = i - n*K;
    float v = w[(size_t)k*N + n];
    short h = f2bs(v);
    wth[i] = h;
    wtl[i] = f2bs(v - bs2f(h));
}

// ---------- 3-tap pool, 4 channels/thread, single-plane out ----------
template<typename TOUT>
__global__ __launch_bounds__(256) void k_pool4(const float* __restrict__ xin,
    const int* __restrict__ col, const float* __restrict__ val, TOUT* __restrict__ out,
    int total4, int c4mask, int cs, int vomask, int vos, int Vi, int bs, int ept4)
{
    int i, c4, r, t;
    if (bs >= 0){
        int rem; swz_t(blockIdx.x, bs, t, rem);
        int il = rem*256 + threadIdx.x;
        i = t*ept4 + il;
        c4 = il & c4mask;
        r  = (il >> cs) & vomask;
    } else {
        i = blockIdx.x*256 + threadIdx.x;
        if (i >= total4) return;
        c4 = i & c4mask;
        int rv = i >> cs;
        r  = rv & vomask;
        t  = rv >> vos;
    }
    int C  = (c4mask + 1) << 2;
    const float* xt = xin + (size_t)t * Vi * C;
    int r3 = 3*r;
    int j0 = col[r3], j1 = col[r3+1], j2 = col[r3+2];
    float v0 = val[r3], v1 = val[r3+1], v2 = val[r3+2];
    int c = c4 << 2;
    float4 a = *(const float4*)&xt[(size_t)j0*C + c];
    float4 b = *(const float4*)&xt[(size_t)j1*C + c];
    float4 d = *(const float4*)&xt[(size_t)j2*C + c];
    float4 o;
    o.x = v0*a.x + v1*b.x + v2*d.x;
    o.y = v0*a.y + v1*b.y + v2*d.y;
    o.z = v0*a.z + v1*b.z + v2*d.z;
    o.w = v0*a.w + v1*b.w + v2*d.w;
    sto4(&out[(size_t)i << 2], o);
}

// ---------- 3-tap pool, dual bf16 hi/lo planes out (split-at-pool) ----------
__global__ __launch_bounds__(256) void k_pool4hl(const float* __restrict__ xin,
    const int* __restrict__ col, const float* __restrict__ val,
    bf16* __restrict__ outh, bf16* __restrict__ outl,
    int c4mask, int cs, int vomask, int Vi, int bs, int ept4)
{
    int t, rem; swz_t(blockIdx.x, bs, t, rem);
    int il = rem*256 + threadIdx.x;
    int i = t*ept4 + il;
    int c4 = il & c4mask;
    int r  = (il >> cs) & vomask;
    int C  = (c4mask + 1) << 2;
    const float* xt = xin + (size_t)t * Vi * C;
    int r3 = 3*r;
    int j0 = col[r3], j1 = col[r3+1], j2 = col[r3+2];
    float v0 = val[r3], v1 = val[r3+1], v2 = val[r3+2];
    int c = c4 << 2;
    float4 a = *(const float4*)&xt[(size_t)j0*C + c];
    float4 b = *(const float4*)&xt[(size_t)j1*C + c];
    float4 d = *(const float4*)&xt[(size_t)j2*C + c];
    float4 o;
    o.x = v0*a.x + v1*b.x + v2*d.x;
    o.y = v0*a.y + v1*b.y + v2*d.y;
    o.z = v0*a.z + v1*b.z + v2*d.z;
    o.w = v0*a.w + v1*b.w + v2*d.w;
    short4 hi; hi.x=f2bs(o.x); hi.y=f2bs(o.y); hi.z=f2bs(o.z); hi.w=f2bs(o.w);
    short4 lo;
    lo.x=f2bs(o.x - bs2f(hi.x)); lo.y=f2bs(o.y - bs2f(hi.y));
    lo.z=f2bs(o.z - bs2f(hi.z)); lo.w=f2bs(o.w - bs2f(hi.w));
    *(short4*)&outh[(size_t)i << 2] = hi;
    *(short4*)&outl[(size_t)i << 2] = lo;
}

// ---------- MFMA spiral conv + ELU, split-precision, XCD-swizzled ----------
// Inputs are bf16 planes xh (+xl if ASPLIT). acc += ah*wh + ah*wl + (ASPLIT? al*wh).
// Block: 256 threads = 4 waves; M-tile 64, full N, K-tile 64; 16-B staging loads.
template<int N, typename TOUT, bool ASPLIT>
__global__ __launch_bounds__(256) void k_conv_mfma(
    const bf16* __restrict__ xh, const bf16* __restrict__ xl,
    const int* __restrict__ spiral, const short* __restrict__ wth, const short* __restrict__ wtl,
    const float* __restrict__ bias, TOUT* __restrict__ out,
    int vshift, int cshift, int K, int swzshift)
{
    __shared__ short lds_ah[64*72];
    __shared__ short lds_al[ASPLIT ? 64*72 : 8];
    __shared__ short lds_bh[N*72];
    __shared__ short lds_bl[N*72];
    const int tid = threadIdx.x;
    int tswz, mt; swz_t(blockIdx.x, swzshift, tswz, mt);
    const int mbase = (tswz << vshift) + mt*64;
    const int lane = tid & 63;
    const int wv = tid >> 6;
    const int col = lane & 15;
    const int quad = lane >> 4;
    const int m0 = wv * 16;
    const int Cm1 = (1 << cshift) - 1;

    f32x4 acc[N/16];
    #pragma unroll
    for (int f = 0; f < N/16; f++){
        float bv = bias[f*16 + col];
        acc[f] = (f32x4){bv, bv, bv, bv};
    }

    const int ntile = K >> 6;
    for (int kt = 0; kt < ntile; kt++){
        int kt0 = kt << 6;
        // stage A: 64 rows x 8 short8-slots (16-B loads)
        #pragma unroll
        for (int e = tid; e < 512; e += 256){
            int m = e >> 3, kk = (e & 7) << 3;
            int gm = mbase + m;
            int t = gm >> vshift, v = gm - (t << vshift);
            int k = kt0 + kk;
            int s = k >> cshift, c = k & Cm1;
            int j = spiral[v*9 + s];
            size_t base = ((((size_t)t << vshift) + j) << cshift) + c;
            *(short8v*)&lds_ah[m*72 + kk] = *(const short8v*)&xh[base];
            if (ASPLIT)
                *(short8v*)&lds_al[m*72 + kk] = *(const short8v*)&xl[base];
        }
        // stage B: N rows x 8 short8-slots
        for (int e = tid; e < N*8; e += 256){
            int n = e >> 3, kk = (e & 7) << 3;
            *(short8v*)&lds_bh[n*72 + kk] = *(const short8v*)&wth[n*K + kt0 + kk];
            *(short8v*)&lds_bl[n*72 + kk] = *(const short8v*)&wtl[n*K + kt0 + kk];
        }
        __syncthreads();
        #pragma unroll
        for (int ks = 0; ks < 64; ks += 32){
            short8v ah = *(short8v*)&lds_ah[(m0 + col)*72 + ks + quad*8];
            short8v al;
            if (ASPLIT) al = *(short8v*)&lds_al[(m0 + col)*72 + ks + quad*8];
            #pragma unroll
            for (int f = 0; f < N/16; f++){
                short8v bh = *(short8v*)&lds_bh[(f*16 + col)*72 + ks + quad*8];
                short8v bl = *(short8v*)&lds_bl[(f*16 + col)*72 + ks + quad*8];
                acc[f] = __builtin_amdgcn_mfma_f32_16x16x32_bf16(ah, bh, acc[f], 0, 0, 0);
                acc[f] = __builtin_amdgcn_mfma_f32_16x16x32_bf16(ah, bl, acc[f], 0, 0, 0);
                if (ASPLIT)
                    acc[f] = __builtin_amdgcn_mfma_f32_16x16x32_bf16(al, bh, acc[f], 0, 0, 0);
            }
        }
        __syncthreads();
    }
    // epilogue: C/D layout col=lane&15, row=quad*4+reg
    #pragma unroll
    for (int f = 0; f < N/16; f++){
        #pragma unroll
        for (int r = 0; r < 4; r++){
            int row = m0 + quad*4 + r;
            float vv = acc[f][r];
            vv = vv > 0.f ? vv : __expf(vv) - 1.f;
            sto(&out[(size_t)(mbase + row)*N + f*16 + col], vv);
        }
    }
}

// ---------- VALU spiral conv (encoder; tiny) ----------
template<typename TIN>
__global__ __launch_bounds__(256) void k_conv(const TIN* __restrict__ xin,
    const int* __restrict__ spiral, const float* __restrict__ w, const float* __restrict__ bias,
    float* __restrict__ out, int TV, int V, int vshift, int C, int O2, int o2shift,
    int K, int KP, int MT)
{
    extern __shared__ float lds[];
    const int S = 9;
    int tid = threadIdx.x;
    int O = O2 << 1;
    int gmbase = blockIdx.x * MT;

    int total = MT * K;
    for (int e = tid; e < total; e += 256){
        int m = e / K, k = e - m*K;
        int gm = gmbase + m;
        if (gm < TV){
            int t = gm >> vshift, v = gm & (V-1);
            int s = k / C, c = k - s*C;
            int j = spiral[v*S + s];
            lds[m*KP + k] = tof(xin[((size_t)t*V + j)*C + c]);
        }
    }
    __syncthreads();

    int m = tid >> o2shift;
    int o = tid & (O2 - 1);
    int gm = gmbase + m;
    if (gm >= TV) return;
    const float* g  = lds + m*KP;
    const float* wp = w + 2*o;
    float acc0 = bias[2*o];
    float acc1 = bias[2*o+1];
    int K4 = K & ~3;
    for (int k = 0; k < K4; k += 4){
        float4 g4 = *(const float4*)(g + k);
        float2 w0 = *(const float2*)(wp + (size_t)k    *O);
        float2 w1 = *(const float2*)(wp + (size_t)(k+1)*O);
        float2 w2 = *(const float2*)(wp + (size_t)(k+2)*O);
        float2 w3 = *(const float2*)(wp + (size_t)(k+3)*O);
        acc0 += g4.x*w0.x + g4.y*w1.x + g4.z*w2.x + g4.w*w3.x;
        acc1 += g4.x*w0.y + g4.y*w1.y + g4.z*w2.y + g4.w*w3.y;
    }
    for (int k = K4; k < K; k++){
        float gv = g[k];
        acc0 += gv * wp[(size_t)k*O];
        acc1 += gv * wp[(size_t)k*O + 1];
    }
    acc0 = acc0 > 0.f ? acc0 : __expf(acc0) - 1.f;
    acc1 = acc1 > 0.f ? acc1 : __expf(acc1) - 1.f;
    float2 r; r.x = acc0; r.y = acc1;
    *(float2*)(out + (size_t)gm*O + 2*o) = r;
}

// ---------- final conv (O=3, no ELU) + actor residual; bf16 input, 16-B gather ----------
__global__ __launch_bounds__(256) void k_outconv(const bf16* __restrict__ xin,
    const int* __restrict__ spiral, const float* __restrict__ w, const float* __restrict__ bias,
    const float* __restrict__ actor, float* __restrict__ out, int vshift, int bs)
{
    int t, rem; swz_t(blockIdx.x, bs, t, rem);
    int v = rem*256 + threadIdx.x;
    size_t i = ((size_t)t << vshift) + v;
    const bf16* xt = xin + (((size_t)t << vshift)) * 32;
    float a0 = bias[0], a1 = bias[1], a2 = bias[2];
    #pragma unroll
    for (int s = 0; s < 9; s++){
        int j = spiral[v*9 + s];
        const short8v* xr = (const short8v*)(xt + (size_t)j*32);
        #pragma unroll
        for (int h = 0; h < 4; h++){
            short8v sv = xr[h];
            const float* wr = w + (s*32 + h*8)*3;
            #pragma unroll
            for (int q = 0; q < 8; q++){
                float xv = bsu2f(sv[q]);
                a0 += xv * wr[q*3];
                a1 += xv * wr[q*3+1];
                a2 += xv * wr[q*3+2];
            }
        }
    }
    a0 += actor[v*3]; a1 += actor[v*3+1]; a2 += actor[v*3+2];
    out[i*3]   = a0;
    out[i*3+1] = a1;
    out[i*3+2] = a2;
}

extern "C" void kernel_launch(void* const* d_in, const int* in_sizes, int n_in,
                              void* d_out, int out_size, void* d_ws, size_t ws_size,
                              hipStream_t stream)
{
    (void)n_in; (void)out_size; (void)ws_size;
    const float* hs        = (const float*)d_in[0];
    const float* actor     = (const float*)d_in[1];
    const float* audio_w   = (const float*)d_in[2];
    const float* audio_b   = (const float*)d_in[3];
    const float* enc_w[4]  = {(const float*)d_in[4],(const float*)d_in[6],(const float*)d_in[8],(const float*)d_in[10]};
    const float* enc_b[4]  = {(const float*)d_in[5],(const float*)d_in[7],(const float*)d_in[9],(const float*)d_in[11]};
    const float* enc_lat_w = (const float*)d_in[12];
    const float* enc_lat_b = (const float*)d_in[13];
    const float* dec_lin_w = (const float*)d_in[14];
    const float* dec_lin_b = (const float*)d_in[15];
    const float* dec_w[4]  = {(const float*)d_in[16],(const float*)d_in[18],(const float*)d_in[20],(const float*)d_in[22]};
    const float* dec_b[4]  = {(const float*)d_in[17],(const float*)d_in[19],(const float*)d_in[21],(const float*)d_in[23]};
    const float* dec_out_w = (const float*)d_in[24];
    const float* dec_out_b = (const float*)d_in[25];
    const int*   spiral[4] = {(const int*)d_in[26],(const int*)d_in[27],(const int*)d_in[28],(const int*)d_in[29]};

    const int* dcol[4]; const float* dval[4]; const int* ucol[4]; const float* uval[4];
    bool interleaved = (in_sizes[33] == 3*8192);
    for (int i = 0; i < 4; i++){
        if (interleaved){
            int b = 30 + 6*i;
            dcol[i] = (const int*)d_in[b+1]; dval[i] = (const float*)d_in[b+2];
            ucol[i] = (const int*)d_in[b+4]; uval[i] = (const float*)d_in[b+5];
        } else {
            dcol[i] = (const int*)d_in[31+3*i]; dval[i] = (const float*)d_in[32+3*i];
            ucol[i] = (const int*)d_in[43+3*i]; uval[i] = (const float*)d_in[44+3*i];
        }
    }

    // ---- workspace (~125 MB) ----
    char* ws = (char*)d_ws;
    size_t off = 0;
    auto alloc = [&](size_t bytes)->char* {
        char* p = ws + off; off += (bytes + 255) & ~(size_t)255; return p;
    };
    float* encX0 = (float*)alloc((size_t)262144*4);
    float* encP0 = (float*)alloc((size_t)65536*4);
    float* encX1 = (float*)alloc((size_t)131072*4);
    float* encP1 = (float*)alloc((size_t)32768*4);
    float* encX2 = (float*)alloc((size_t)32768*4);
    float* encP2 = (float*)alloc((size_t)8192*4);
    float* encX3 = (float*)alloc((size_t)16384*4);
    float* encP3 = (float*)alloc((size_t)4096*4);
    float* aemb  = (float*)alloc((size_t)4096*4);
    float* pemb  = (float*)alloc((size_t)64*4);
    short* wt0h  = (short*)alloc((size_t)147456*2);   // dec0 [128][1152]
    short* wt0l  = (short*)alloc((size_t)147456*2);
    short* wt1h  = (short*)alloc((size_t)73728*2);    // dec1 [64][1152]
    short* wt1l  = (short*)alloc((size_t)73728*2);
    short* wt2h  = (short*)alloc((size_t)36864*2);    // dec2 [64][576]
    short* wt2l  = (short*)alloc((size_t)36864*2);
    short* wt3h  = (short*)alloc((size_t)18432*2);    // dec3 [32][576]
    short* wt3l  = (short*)alloc((size_t)18432*2);
    char*  Praw  = alloc((size_t)36*1048576);         // conv outputs (f32 / bf16 views)
    bf16*  Qh    = (bf16*)alloc((size_t)68*1048576);  // pool out hi plane
    bf16*  Ql    = (bf16*)alloc((size_t)17*1048576);  // pool out lo plane
    float* P  = (float*)Praw;
    bf16*  Pb = (bf16*)Praw;

    // ---- prep ----
    k_audio<<<64,64,0,stream>>>(hs, audio_w, audio_b, aemb);
    k_wtr<<<576,256,0,stream>>>(dec_w[0], wt0h, wt0l, 1152, 128);
    k_wtr<<<288,256,0,stream>>>(dec_w[1], wt1h, wt1l, 1152, 64);
    k_wtr<<<144,256,0,stream>>>(dec_w[2], wt2h, wt2l, 576, 64);
    k_wtr<<<72,256,0,stream>>>(dec_w[3], wt3h, wt3l, 576, 32);

    // ---- encoder (VALU; tiny, B=1) ----
    k_conv<float><<<512,256, 16*28*4, stream>>>(actor, spiral[0], enc_w[0], enc_b[0], encX0, 8192, 8192,13,   3,16,4,  27,  28,16);
    k_pool4<float><<<64,256,0,stream>>>(encX0, dcol[0], dval[0], encP0, 16384, 7,3, 2047,11, 8192, -1,0);
    k_conv<float><<<256,256, 8*292*4, stream>>>(encP0, spiral[1], enc_w[1], enc_b[1], encX1, 2048, 2048,11,  32,32,5, 288, 292, 8);
    k_pool4<float><<<32,256,0,stream>>>(encX1, dcol[1], dval[1], encP1, 8192, 15,4, 511,9, 2048, -1,0);
    k_conv<float><<<64,256, 8*580*4, stream>>>(encP1, spiral[2], enc_w[2], enc_b[2], encX2, 512, 512,9,  64,32,5, 576, 580, 8);
    k_pool4<float><<<8,256,0,stream>>>(encX2, dcol[2], dval[2], encP2, 2048, 15,4, 127,7, 512, -1,0);
    k_conv<float><<<32,256, 4*580*4, stream>>>(encP2, spiral[3], enc_w[3], enc_b[3], encX3, 128, 128,7,  64,64,6, 576, 580, 4);
    k_pool4<float><<<4,256,0,stream>>>(encX3, dcol[3], dval[3], encP3, 1024, 31,5, 31,5, 128, -1,0);
    k_enclat<<<64,256,0,stream>>>(encP3, enc_lat_w, enc_lat_b, pemb);

    // ---- decoder (XCD t-swizzled) ----
    k_declin<<<dim3(16,64),256,0,stream>>>(aemb, pemb, dec_lin_w, dec_lin_b, P);  // [64,32,128] f32

    k_pool4hl<<<1024,256,0,stream>>>(P, ucol[3], uval[3], Qh, Ql, 31,5, 127, 32, 4, 4096);       // ->[64,128,128] hi/lo
    k_conv_mfma<128,float,true><<<128,256,0,stream>>>(Qh, Ql, spiral[3], wt0h, wt0l, dec_b[0], P, 7, 7, 1152, 1);   // ->[64,128,128] f32

    k_pool4hl<<<4096,256,0,stream>>>(P, ucol[2], uval[2], Qh, Ql, 31,5, 511, 128, 6, 16384);     // ->[64,512,128] hi/lo
    k_conv_mfma<64,float,true><<<512,256,0,stream>>>(Qh, Ql, spiral[2], wt1h, wt1l, dec_b[1], P, 9, 7, 1152, 3);    // ->[64,512,64] f32

    k_pool4hl<<<8192,256,0,stream>>>(P, ucol[1], uval[1], Qh, Ql, 15,4, 2047, 512, 7, 32768);    // ->[64,2048,64] hi/lo
    k_conv_mfma<64,float,true><<<2048,256,0,stream>>>(Qh, Ql, spiral[1], wt2h, wt2l, dec_b[2], P, 11, 6, 576, 5);   // ->[64,2048,64] f32

    k_pool4<bf16><<<32768,256,0,stream>>>(P, ucol[0], uval[0], Qh, 8388608, 15,4, 8191,13, 2048, 9, 131072);        // ->[64,8192,64] bf16
    k_conv_mfma<32,bf16,false><<<8192,256,0,stream>>>(Qh, (const bf16*)nullptr, spiral[0], wt3h, wt3l, dec_b[3], Pb, 13, 6, 576, 7); // ->[64,8192,32] bf16

    k_outconv<<<2048,256,0,stream>>>(Pb, spiral[0], dec_out_w, dec_out_b, actor, (float*)d_out, 13, 5);
}

// Round 8
// 630.015 us; speedup vs baseline: 7.3258x; 1.0656x over previous
//
#include <hip/hip_runtime.h>
#include <hip/hip_bf16.h>

typedef __hip_bfloat16 bf16;
typedef __attribute__((ext_vector_type(8))) short short8v;
typedef __attribute__((ext_vector_type(16))) float f32x16;

__device__ __forceinline__ float tof(float v){ return v; }
__device__ __forceinline__ float tof(bf16 v){ return __bfloat162float(v); }
__device__ __forceinline__ void sto(float* p, float v){ *p = v; }
__device__ __forceinline__ void sto(bf16* p, float v){ *p = __float2bfloat16(v); }
__device__ __forceinline__ short f2bs(float f){ bf16 h = __float2bfloat16(f); return *(short*)&h; }
__device__ __forceinline__ float bsu2f(short s){
    return __uint_as_float(((unsigned)(unsigned short)s) << 16);
}

__device__ __forceinline__ void sto4(float* p, float4 v){ *(float4*)p = v; }
__device__ __forceinline__ void sto4(bf16* p, float4 v){
    short4 s; s.x=f2bs(v.x); s.y=f2bs(v.y); s.z=f2bs(v.z); s.w=f2bs(v.w);
    *(short4*)p = s;
}

// XCD-aware swizzle for 64-frame (t) problems: grid = 64 << bs blocks,
// block b -> xcd = b&7 (round-robin dispatch), per-XCD t-range of 8 frames.
__device__ __forceinline__ void swz_t(int b, int bs, int& t, int& rem){
    int x = b & 7, k = b >> 3;
    t = x*8 + (k >> bs);
    rem = k & ((1 << bs) - 1);
}

// ---------- audio embedding ----------
__global__ __launch_bounds__(64) void k_audio(const float* __restrict__ hs,
    const float* __restrict__ w, const float* __restrict__ b, float* __restrict__ out)
{
    int t = blockIdx.x, l = threadIdx.x;
    float acc = b[l];
    const float* h = hs + t*768;
    #pragma unroll 4
    for (int k = 0; k < 768; k++) acc += h[k] * w[k*64 + l];
    out[t*64 + l] = acc;
}

// ---------- enc_lat ----------
__global__ __launch_bounds__(256) void k_enclat(const float* __restrict__ flat,
    const float* __restrict__ w, const float* __restrict__ b, float* __restrict__ out)
{
    __shared__ float red[256];
    int l = blockIdx.x, tid = threadIdx.x;
    float acc = 0.f;
    for (int k = tid; k < 4096; k += 256) acc += flat[k] * w[k*64 + l];
    red[tid] = acc; __syncthreads();
    for (int s = 128; s > 0; s >>= 1){ if (tid < s) red[tid] += red[tid+s]; __syncthreads(); }
    if (tid == 0) out[l] = red[0] + b[l];
}

// ---------- dec_lin fused with latent concat ----------
__global__ __launch_bounds__(256) void k_declin(const float* __restrict__ ae,
    const float* __restrict__ pe, const float* __restrict__ w, const float* __restrict__ b,
    float* __restrict__ out)
{
    int n = blockIdx.x*256 + threadIdx.x;
    int t = blockIdx.y;
    float acc = b[n];
    const float* a = ae + t*64;
    #pragma unroll 8
    for (int k = 0; k < 64; k++) acc += a[k]  * w[k*4096 + n];
    #pragma unroll 8
    for (int k = 0; k < 64; k++) acc += pe[k] * w[(64+k)*4096 + n];
    out[(size_t)t*4096 + n] = acc;
}

// ---------- weight transpose+convert: wt[n*K+k] = bf16(w[k*N+n]) ----------
__global__ __launch_bounds__(256) void k_wtr(const float* __restrict__ w,
    short* __restrict__ wt, int K, int N)
{
    int i = blockIdx.x*256 + threadIdx.x;
    if (i >= K*N) return;
    int n = i / K, k = i - n*K;
    wt[i] = f2bs(w[(size_t)k*N + n]);
}

// ---------- 3-tap pool, 4 channels/thread ----------
template<typename TOUT>
__global__ __launch_bounds__(256) void k_pool4(const float* __restrict__ xin,
    const int* __restrict__ col, const float* __restrict__ val, TOUT* __restrict__ out,
    int total4, int c4mask, int cs, int vomask, int vos, int Vi, int bs, int ept4)
{
    int i, c4, r, t;
    if (bs >= 0){
        int rem; swz_t(blockIdx.x, bs, t, rem);
        int il = rem*256 + threadIdx.x;
        i = t*ept4 + il;
        c4 = il & c4mask;
        r  = (il >> cs) & vomask;
    } else {
        i = blockIdx.x*256 + threadIdx.x;
        if (i >= total4) return;
        c4 = i & c4mask;
        int rv = i >> cs;
        r  = rv & vomask;
        t  = rv >> vos;
    }
    int C  = (c4mask + 1) << 2;
    const float* xt = xin + (size_t)t * Vi * C;
    int r3 = 3*r;
    int j0 = col[r3], j1 = col[r3+1], j2 = col[r3+2];
    float v0 = val[r3], v1 = val[r3+1], v2 = val[r3+2];
    int c = c4 << 2;
    float4 a = *(const float4*)&xt[(size_t)j0*C + c];
    float4 b = *(const float4*)&xt[(size_t)j1*C + c];
    float4 d = *(const float4*)&xt[(size_t)j2*C + c];
    float4 o;
    o.x = v0*a.x + v1*b.x + v2*d.x;
    o.y = v0*a.y + v1*b.y + v2*d.y;
    o.z = v0*a.z + v1*b.z + v2*d.z;
    o.w = v0*a.w + v1*b.w + v2*d.w;
    sto4(&out[(size_t)i << 2], o);
}

// ---------- MFMA(32x32x16) spiral conv + ELU, bf16, XCD-swizzled ----------
// C[m][n] = elu(bias[n] + sum_k A[m][k]*W[k][n]); A gathered via spiral (bf16 planes).
// Block 256 thr = 4 waves; M-tile 128 (32 rows/wave); K-tile 64; grid = 64<<swzshift.
// A frag: m=lane&31, k=(lane>>5)*8+j ; B frag from wt[n][k]: n=lane&31, same k.
// C/D: col=lane&31, row=(reg&3)+8*(reg>>2)+4*(lane>>5)   [verified m74/m101]
template<int N, typename TOUT>
__global__ __launch_bounds__(256) void k_conv_mfma32(
    const bf16* __restrict__ xin, const int* __restrict__ spiral,
    const short* __restrict__ wt, const float* __restrict__ bias, TOUT* __restrict__ out,
    int vshift, int cshift, int K, int swzshift)
{
    __shared__ short lds_a[128*72];
    __shared__ short lds_b[N*72];
    const int tid = threadIdx.x;
    int tswz, mt; swz_t(blockIdx.x, swzshift, tswz, mt);
    const int mbase = (tswz << vshift) + mt*128;
    const int lane = tid & 63;
    const int wv = tid >> 6;
    const int col = lane & 31;
    const int half = lane >> 5;
    const int m0 = wv * 32;
    const int Cm1 = (1 << cshift) - 1;
    const int Vm1 = (1 << vshift) - 1;

    f32x16 acc[N/32];
    #pragma unroll
    for (int f = 0; f < N/32; f++){
        float bv = bias[f*32 + col];
        #pragma unroll
        for (int r = 0; r < 16; r++) acc[f][r] = bv;
    }

    const int ntile = K >> 6;
    for (int kt = 0; kt < ntile; kt++){
        int kt0 = kt << 6;
        // stage A: 128 rows x 8 short8-slots (16-B loads), 4 per thread
        #pragma unroll
        for (int e = tid; e < 1024; e += 256){
            int m = e >> 3, kk = (e & 7) << 3;
            int gm = mbase + m;
            int t = gm >> vshift, v = gm & Vm1;
            int k = kt0 + kk;
            int s = k >> cshift, c = k & Cm1;
            int j = spiral[v*9 + s];
            *(short8v*)&lds_a[m*72 + kk] =
                *(const short8v*)&xin[((((size_t)t << vshift) + j) << cshift) + c];
        }
        // stage B: N rows x 8 short8-slots
        #pragma unroll
        for (int e = tid; e < N*8; e += 256){
            int n = e >> 3, kk = (e & 7) << 3;
            *(short8v*)&lds_b[n*72 + kk] = *(const short8v*)&wt[n*K + kt0 + kk];
        }
        __syncthreads();
        #pragma unroll
        for (int ks = 0; ks < 64; ks += 16){
            short8v a = *(short8v*)&lds_a[(m0 + col)*72 + ks + half*8];
            #pragma unroll
            for (int f = 0; f < N/32; f++){
                short8v b = *(short8v*)&lds_b[(f*32 + col)*72 + ks + half*8];
                acc[f] = __builtin_amdgcn_mfma_f32_32x32x16_bf16(a, b, acc[f], 0, 0, 0);
            }
        }
        __syncthreads();
    }
    // epilogue
    #pragma unroll
    for (int f = 0; f < N/32; f++){
        #pragma unroll
        for (int r = 0; r < 16; r++){
            int row = (r & 3) + 8*(r >> 2) + 4*half;
            float vv = acc[f][r];
            vv = vv > 0.f ? vv : __expf(vv) - 1.f;
            sto(&out[(size_t)(mbase + m0 + row)*N + f*32 + col], vv);
        }
    }
}

// ---------- VALU spiral conv (encoder; tiny) ----------
template<typename TIN>
__global__ __launch_bounds__(256) void k_conv(const TIN* __restrict__ xin,
    const int* __restrict__ spiral, const float* __restrict__ w, const float* __restrict__ bias,
    float* __restrict__ out, int TV, int V, int vshift, int C, int O2, int o2shift,
    int K, int KP, int MT)
{
    extern __shared__ float lds[];
    const int S = 9;
    int tid = threadIdx.x;
    int O = O2 << 1;
    int gmbase = blockIdx.x * MT;

    int total = MT * K;
    for (int e = tid; e < total; e += 256){
        int m = e / K, k = e - m*K;
        int gm = gmbase + m;
        if (gm < TV){
            int t = gm >> vshift, v = gm & (V-1);
            int s = k / C, c = k - s*C;
            int j = spiral[v*S + s];
            lds[m*KP + k] = tof(xin[((size_t)t*V + j)*C + c]);
        }
    }
    __syncthreads();

    int m = tid >> o2shift;
    int o = tid & (O2 - 1);
    int gm = gmbase + m;
    if (gm >= TV) return;
    const float* g  = lds + m*KP;
    const float* wp = w + 2*o;
    float acc0 = bias[2*o];
    float acc1 = bias[2*o+1];
    int K4 = K & ~3;
    for (int k = 0; k < K4; k += 4){
        float4 g4 = *(const float4*)(g + k);
        float2 w0 = *(const float2*)(wp + (size_t)k    *O);
        float2 w1 = *(const float2*)(wp + (size_t)(k+1)*O);
        float2 w2 = *(const float2*)(wp + (size_t)(k+2)*O);
        float2 w3 = *(const float2*)(wp + (size_t)(k+3)*O);
        acc0 += g4.x*w0.x + g4.y*w1.x + g4.z*w2.x + g4.w*w3.x;
        acc1 += g4.x*w0.y + g4.y*w1.y + g4.z*w2.y + g4.w*w3.y;
    }
    for (int k = K4; k < K; k++){
        float gv = g[k];
        acc0 += gv * wp[(size_t)k*O];
        acc1 += gv * wp[(size_t)k*O + 1];
    }
    acc0 = acc0 > 0.f ? acc0 : __expf(acc0) - 1.f;
    acc1 = acc1 > 0.f ? acc1 : __expf(acc1) - 1.f;
    float2 r; r.x = acc0; r.y = acc1;
    *(float2*)(out + (size_t)gm*O + 2*o) = r;
}

// ---------- final conv (O=3, no ELU) + actor residual; bf16 input, 16-B gather ----------
__global__ __launch_bounds__(256) void k_outconv(const bf16* __restrict__ xin,
    const int* __restrict__ spiral, const float* __restrict__ w, const float* __restrict__ bias,
    const float* __restrict__ actor, float* __restrict__ out, int vshift, int bs)
{
    int t, rem; swz_t(blockIdx.x, bs, t, rem);
    int v = rem*256 + threadIdx.x;
    size_t i = ((size_t)t << vshift) + v;
    const bf16* xt = xin + (((size_t)t << vshift)) * 32;
    float a0 = bias[0], a1 = bias[1], a2 = bias[2];
    #pragma unroll
    for (int s = 0; s < 9; s++){
        int j = spiral[v*9 + s];
        const short8v* xr = (const short8v*)(xt + (size_t)j*32);
        #pragma unroll
        for (int h = 0; h < 4; h++){
            short8v sv = xr[h];
            const float* wr = w + (s*32 + h*8)*3;
            #pragma unroll
            for (int q = 0; q < 8; q++){
                float xv = bsu2f(sv[q]);
                a0 += xv * wr[q*3];
                a1 += xv * wr[q*3+1];
                a2 += xv * wr[q*3+2];
            }
        }
    }
    a0 += actor[v*3]; a1 += actor[v*3+1]; a2 += actor[v*3+2];
    out[i*3]   = a0;
    out[i*3+1] = a1;
    out[i*3+2] = a2;
}

extern "C" void kernel_launch(void* const* d_in, const int* in_sizes, int n_in,
                              void* d_out, int out_size, void* d_ws, size_t ws_size,
                              hipStream_t stream)
{
    (void)n_in; (void)out_size; (void)ws_size;
    const float* hs        = (const float*)d_in[0];
    const float* actor     = (const float*)d_in[1];
    const float* audio_w   = (const float*)d_in[2];
    const float* audio_b   = (const float*)d_in[3];
    const float* enc_w[4]  = {(const float*)d_in[4],(const float*)d_in[6],(const float*)d_in[8],(const float*)d_in[10]};
    const float* enc_b[4]  = {(const float*)d_in[5],(const float*)d_in[7],(const float*)d_in[9],(const float*)d_in[11]};
    const float* enc_lat_w = (const float*)d_in[12];
    const float* enc_lat_b = (const float*)d_in[13];
    const float* dec_lin_w = (const float*)d_in[14];
    const float* dec_lin_b = (const float*)d_in[15];
    const float* dec_w[4]  = {(const float*)d_in[16],(const float*)d_in[18],(const float*)d_in[20],(const float*)d_in[22]};
    const float* dec_b[4]  = {(const float*)d_in[17],(const float*)d_in[19],(const float*)d_in[21],(const float*)d_in[23]};
    const float* dec_out_w = (const float*)d_in[24];
    const float* dec_out_b = (const float*)d_in[25];
    const int*   spiral[4] = {(const int*)d_in[26],(const int*)d_in[27],(const int*)d_in[28],(const int*)d_in[29]};

    const int* dcol[4]; const float* dval[4]; const int* ucol[4]; const float* uval[4];
    bool interleaved = (in_sizes[33] == 3*8192);
    for (int i = 0; i < 4; i++){
        if (interleaved){
            int b = 30 + 6*i;
            dcol[i] = (const int*)d_in[b+1]; dval[i] = (const float*)d_in[b+2];
            ucol[i] = (const int*)d_in[b+4]; uval[i] = (const float*)d_in[b+5];
        } else {
            dcol[i] = (const int*)d_in[31+3*i]; dval[i] = (const float*)d_in[32+3*i];
            ucol[i] = (const int*)d_in[43+3*i]; uval[i] = (const float*)d_in[44+3*i];
        }
    }

    // ---- workspace ----
    char* ws = (char*)d_ws;
    size_t off = 0;
    auto alloc = [&](size_t bytes)->char* {
        char* p = ws + off; off += (bytes + 255) & ~(size_t)255; return p;
    };
    float* encX0 = (float*)alloc((size_t)262144*4);
    float* encP0 = (float*)alloc((size_t)65536*4);
    float* encX1 = (float*)alloc((size_t)131072*4);
    float* encP1 = (float*)alloc((size_t)32768*4);
    float* encX2 = (float*)alloc((size_t)32768*4);
    float* encP2 = (float*)alloc((size_t)8192*4);
    float* encX3 = (float*)alloc((size_t)16384*4);
    float* encP3 = (float*)alloc((size_t)4096*4);
    float* aemb  = (float*)alloc((size_t)4096*4);
    float* pemb  = (float*)alloc((size_t)64*4);
    short* wt0   = (short*)alloc((size_t)147456*2);   // dec0 [128][1152]
    short* wt1   = (short*)alloc((size_t)73728*2);    // dec1 [64][1152]
    short* wt2   = (short*)alloc((size_t)36864*2);    // dec2 [64][576]
    short* wt3   = (short*)alloc((size_t)18432*2);    // dec3 [32][576]
    char*  Praw  = alloc((size_t)36*1048576);         // conv outputs (f32 / bf16 views)
    bf16*  Qb    = (bf16*)alloc((size_t)68*1048576);  // pool outputs (bf16)
    float* P  = (float*)Praw;
    bf16*  Pb = (bf16*)Praw;

    // ---- prep ----
    k_audio<<<64,64,0,stream>>>(hs, audio_w, audio_b, aemb);
    k_wtr<<<576,256,0,stream>>>(dec_w[0], wt0, 1152, 128);
    k_wtr<<<288,256,0,stream>>>(dec_w[1], wt1, 1152, 64);
    k_wtr<<<144,256,0,stream>>>(dec_w[2], wt2, 576, 64);
    k_wtr<<<72,256,0,stream>>>(dec_w[3], wt3, 576, 32);

    // ---- encoder (VALU; tiny, B=1) ----
    k_conv<float><<<512,256, 16*28*4, stream>>>(actor, spiral[0], enc_w[0], enc_b[0], encX0, 8192, 8192,13,   3,16,4,  27,  28,16);
    k_pool4<float><<<64,256,0,stream>>>(encX0, dcol[0], dval[0], encP0, 16384, 7,3, 2047,11, 8192, -1,0);
    k_conv<float><<<256,256, 8*292*4, stream>>>(encP0, spiral[1], enc_w[1], enc_b[1], encX1, 2048, 2048,11,  32,32,5, 288, 292, 8);
    k_pool4<float><<<32,256,0,stream>>>(encX1, dcol[1], dval[1], encP1, 8192, 15,4, 511,9, 2048, -1,0);
    k_conv<float><<<64,256, 8*580*4, stream>>>(encP1, spiral[2], enc_w[2], enc_b[2], encX2, 512, 512,9,  64,32,5, 576, 580, 8);
    k_pool4<float><<<8,256,0,stream>>>(encX2, dcol[2], dval[2], encP2, 2048, 15,4, 127,7, 512, -1,0);
    k_conv<float><<<32,256, 4*580*4, stream>>>(encP2, spiral[3], enc_w[3], enc_b[3], encX3, 128, 128,7,  64,64,6, 576, 580, 4);
    k_pool4<float><<<4,256,0,stream>>>(encX3, dcol[3], dval[3], encP3, 1024, 31,5, 31,5, 128, -1,0);
    k_enclat<<<64,256,0,stream>>>(encP3, enc_lat_w, enc_lat_b, pemb);

    // ---- decoder (XCD t-swizzled, all-bf16 MFMA) ----
    k_declin<<<dim3(16,64),256,0,stream>>>(aemb, pemb, dec_lin_w, dec_lin_b, P);  // [64,32,128] f32

    k_pool4<bf16><<<1024,256,0,stream>>>(P, ucol[3], uval[3], Qb, 262144, 31,5, 127,7, 32, 4, 4096);        // ->[64,128,128] bf16
    k_conv_mfma32<128,float><<<64,256,0,stream>>>(Qb, spiral[3], wt0, dec_b[0], P, 7, 7, 1152, 0);          // ->[64,128,128] f32

    k_pool4<bf16><<<4096,256,0,stream>>>(P, ucol[2], uval[2], Qb, 1048576, 31,5, 511,9, 128, 6, 16384);     // ->[64,512,128] bf16
    k_conv_mfma32<64,float><<<256,256,0,stream>>>(Qb, spiral[2], wt1, dec_b[1], P, 9, 7, 1152, 2);          // ->[64,512,64] f32

    k_pool4<bf16><<<8192,256,0,stream>>>(P, ucol[1], uval[1], Qb, 2097152, 15,4, 2047,11, 512, 7, 32768);   // ->[64,2048,64] bf16
    k_conv_mfma32<64,float><<<1024,256,0,stream>>>(Qb, spiral[1], wt2, dec_b[2], P, 11, 6, 576, 4);         // ->[64,2048,64] f32

    k_pool4<bf16><<<32768,256,0,stream>>>(P, ucol[0], uval[0], Qb, 8388608, 15,4, 8191,13, 2048, 9, 131072);// ->[64,8192,64] bf16
    k_conv_mfma32<32,bf16><<<4096,256,0,stream>>>(Qb, spiral[0], wt3, dec_b[3], Pb, 13, 6, 576, 6);         // ->[64,8192,32] bf16

    k_outconv<<<2048,256,0,stream>>>(Pb, spiral[0], dec_out_w, dec_out_b, actor, (float*)d_out, 13, 5);
}

// Round 9
// 608.367 us; speedup vs baseline: 7.5865x; 1.0356x over previous
//
#include <hip/hip_runtime.h>
#include <hip/hip_bf16.h>

typedef __hip_bfloat16 bf16;
typedef __attribute__((ext_vector_type(8))) short short8v;
typedef __attribute__((ext_vector_type(16))) float f32x16;

__device__ __forceinline__ float tof(float v){ return v; }
__device__ __forceinline__ float tof(bf16 v){ return __bfloat162float(v); }
__device__ __forceinline__ void sto(float* p, float v){ *p = v; }
__device__ __forceinline__ void sto(bf16* p, float v){ *p = __float2bfloat16(v); }
__device__ __forceinline__ short f2bs(float f){ bf16 h = __float2bfloat16(f); return *(short*)&h; }
__device__ __forceinline__ float bsu2f(short s){
    return __uint_as_float(((unsigned)(unsigned short)s) << 16);
}

__device__ __forceinline__ void sto4(float* p, float4 v){ *(float4*)p = v; }
__device__ __forceinline__ void sto4(bf16* p, float4 v){
    short4 s; s.x=f2bs(v.x); s.y=f2bs(v.y); s.z=f2bs(v.z); s.w=f2bs(v.w);
    *(short4*)p = s;
}

// XCD-aware swizzle for 64-frame (t) problems: grid = 64 << bs blocks,
// block b -> xcd = b&7 (round-robin dispatch), per-XCD t-range of 8 frames.
__device__ __forceinline__ void swz_t(int b, int bs, int& t, int& rem){
    int x = b & 7, k = b >> 3;
    t = x*8 + (k >> bs);
    rem = k & ((1 << bs) - 1);
}

// ---------- audio embedding ----------
__global__ __launch_bounds__(64) void k_audio(const float* __restrict__ hs,
    const float* __restrict__ w, const float* __restrict__ b, float* __restrict__ out)
{
    int t = blockIdx.x, l = threadIdx.x;
    float acc = b[l];
    const float* h = hs + t*768;
    #pragma unroll 4
    for (int k = 0; k < 768; k++) acc += h[k] * w[k*64 + l];
    out[t*64 + l] = acc;
}

// ---------- enc_lat ----------
__global__ __launch_bounds__(256) void k_enclat(const float* __restrict__ flat,
    const float* __restrict__ w, const float* __restrict__ b, float* __restrict__ out)
{
    __shared__ float red[256];
    int l = blockIdx.x, tid = threadIdx.x;
    float acc = 0.f;
    for (int k = tid; k < 4096; k += 256) acc += flat[k] * w[k*64 + l];
    red[tid] = acc; __syncthreads();
    for (int s = 128; s > 0; s >>= 1){ if (tid < s) red[tid] += red[tid+s]; __syncthreads(); }
    if (tid == 0) out[l] = red[0] + b[l];
}

// ---------- dec_lin fused with latent concat (float4 weights) ----------
__global__ __launch_bounds__(256) void k_declin4(const float* __restrict__ ae,
    const float* __restrict__ pe, const float* __restrict__ w, const float* __restrict__ b,
    float* __restrict__ out)
{
    int n4 = blockIdx.x*256 + threadIdx.x;   // 0..1023
    int t = blockIdx.y;
    float4 acc = *(const float4*)&b[n4*4];
    const float* a = ae + t*64;
    #pragma unroll 4
    for (int k = 0; k < 64; k++){
        float av = a[k];
        float4 wv = *(const float4*)&w[(size_t)k*4096 + n4*4];
        acc.x += av*wv.x; acc.y += av*wv.y; acc.z += av*wv.z; acc.w += av*wv.w;
    }
    #pragma unroll 4
    for (int k = 0; k < 64; k++){
        float pv = pe[k];
        float4 wv = *(const float4*)&w[(size_t)(64+k)*4096 + n4*4];
        acc.x += pv*wv.x; acc.y += pv*wv.y; acc.z += pv*wv.z; acc.w += pv*wv.w;
    }
    *(float4*)&out[(size_t)t*4096 + n4*4] = acc;
}

// ---------- weight transpose+convert: wt[n*K+k] = bf16(w[k*N+n]) ----------
__global__ __launch_bounds__(256) void k_wtr(const float* __restrict__ w,
    short* __restrict__ wt, int K, int N)
{
    int i = blockIdx.x*256 + threadIdx.x;
    if (i >= K*N) return;
    int n = i / K, k = i - n*K;
    wt[i] = f2bs(w[(size_t)k*N + n]);
}

// ---------- 3-tap pool, 4 channels/thread ----------
template<typename TOUT>
__global__ __launch_bounds__(256) void k_pool4(const float* __restrict__ xin,
    const int* __restrict__ col, const float* __restrict__ val, TOUT* __restrict__ out,
    int total4, int c4mask, int cs, int vomask, int vos, int Vi, int bs, int ept4)
{
    int i, c4, r, t;
    if (bs >= 0){
        int rem; swz_t(blockIdx.x, bs, t, rem);
        int il = rem*256 + threadIdx.x;
        i = t*ept4 + il;
        c4 = il & c4mask;
        r  = (il >> cs) & vomask;
    } else {
        i = blockIdx.x*256 + threadIdx.x;
        if (i >= total4) return;
        c4 = i & c4mask;
        int rv = i >> cs;
        r  = rv & vomask;
        t  = rv >> vos;
    }
    int C  = (c4mask + 1) << 2;
    const float* xt = xin + (size_t)t * Vi * C;
    int r3 = 3*r;
    int j0 = col[r3], j1 = col[r3+1], j2 = col[r3+2];
    float v0 = val[r3], v1 = val[r3+1], v2 = val[r3+2];
    int c = c4 << 2;
    float4 a = *(const float4*)&xt[(size_t)j0*C + c];
    float4 b = *(const float4*)&xt[(size_t)j1*C + c];
    float4 d = *(const float4*)&xt[(size_t)j2*C + c];
    float4 o;
    o.x = v0*a.x + v1*b.x + v2*d.x;
    o.y = v0*a.y + v1*b.y + v2*d.y;
    o.z = v0*a.z + v1*b.z + v2*d.z;
    o.w = v0*a.w + v1*b.w + v2*d.w;
    sto4(&out[(size_t)i << 2], o);
}

// ---------- direct-A MFMA(32x32x16) spiral conv + ELU ----------
// Block 256 thr = 4 waves; each wave computes 32 rows x 32 cols; M-tile 128, N-block 32.
// A fragments loaded per-lane directly from global (16-B, spiral-gathered);
// B (weights) staged to LDS once per 576-K chunk (1-2 barriers total).
// A frag: m=lane&31, k=half*8+j ; B frag: n=lane&31, same k.
// C/D: col=lane&31, row=(reg&3)+8*(reg>>2)+4*half   [verified m74/m101, rounds 8]
template<int NTOT, int KTOT, int CSHIFT, int VSHIFT, typename TOUT>
__global__ __launch_bounds__(256) void k_conv_dg(
    const bf16* __restrict__ xin, const int* __restrict__ spiral,
    const short* __restrict__ wt, const float* __restrict__ bias, TOUT* __restrict__ out,
    int bs)
{
    constexpr int NBLK = NTOT/32;
    constexpr int KC   = (KTOT > 576) ? 576 : KTOT;   // K-chunk
    constexpr int NKC  = KTOT / KC;
    constexpr int Cm1  = (1 << CSHIFT) - 1;
    __shared__ short lds_b[32*580];

    const int tid = threadIdx.x;
    const int lane = tid & 63;
    const int wv = tid >> 6;
    const int col = lane & 31;
    const int half = lane >> 5;

    int t, rem; swz_t(blockIdx.x, bs, t, rem);
    const int vtile = rem / NBLK;
    const int nb = rem - vtile*NBLK;
    const int vrow = vtile*128 + wv*32 + col;

    // preload this lane's spiral row
    int j[9];
    #pragma unroll
    for (int s = 0; s < 9; s++) j[s] = spiral[vrow*9 + s];

    const bf16* xbase = xin + ((size_t)t << (VSHIFT + CSHIFT));

    f32x16 acc;
    {
        float bv = bias[nb*32 + col];
        #pragma unroll
        for (int r = 0; r < 16; r++) acc[r] = bv;
    }

    #pragma unroll
    for (int kc = 0; kc < NKC; kc++){
        const int kbase = kc*KC;
        __syncthreads();
        #pragma unroll
        for (int e = tid; e < 32*(KC/8); e += 256){
            int n = e / (KC/8), kk = (e - n*(KC/8))*8;
            *(short8v*)&lds_b[n*580 + kk] = *(const short8v*)&wt[(size_t)(nb*32 + n)*KTOT + kbase + kk];
        }
        __syncthreads();
        #pragma unroll
        for (int ls = 0; ls < KC/16; ls++){
            int k0 = kbase + ls*16;
            int s = k0 >> CSHIFT;
            int c = (k0 & Cm1) + half*8;
            short8v a = *(const short8v*)&xbase[((size_t)j[s] << CSHIFT) + c];
            short8v b = *(short8v*)&lds_b[col*580 + ls*16 + half*8];
            acc = __builtin_amdgcn_mfma_f32_32x32x16_bf16(a, b, acc, 0, 0, 0);
        }
    }

    // epilogue
    const size_t mb = ((size_t)t << VSHIFT) + vtile*128 + wv*32;
    #pragma unroll
    for (int r = 0; r < 16; r++){
        int row = (r & 3) + 8*(r >> 2) + 4*half;
        float vv = acc[r];
        vv = vv > 0.f ? vv : __expf(vv) - 1.f;
        sto(&out[(mb + row)*NTOT + nb*32 + col], vv);
    }
}

// ---------- VALU spiral conv (encoder; tiny) ----------
template<typename TIN>
__global__ __launch_bounds__(256) void k_conv(const TIN* __restrict__ xin,
    const int* __restrict__ spiral, const float* __restrict__ w, const float* __restrict__ bias,
    float* __restrict__ out, int TV, int V, int vshift, int C, int O2, int o2shift,
    int K, int KP, int MT)
{
    extern __shared__ float lds[];
    const int S = 9;
    int tid = threadIdx.x;
    int O = O2 << 1;
    int gmbase = blockIdx.x * MT;

    int total = MT * K;
    for (int e = tid; e < total; e += 256){
        int m = e / K, k = e - m*K;
        int gm = gmbase + m;
        if (gm < TV){
            int t = gm >> vshift, v = gm & (V-1);
            int s = k / C, c = k - s*C;
            int jj = spiral[v*S + s];
            lds[m*KP + k] = tof(xin[((size_t)t*V + jj)*C + c]);
        }
    }
    __syncthreads();

    int m = tid >> o2shift;
    int o = tid & (O2 - 1);
    int gm = gmbase + m;
    if (gm >= TV) return;
    const float* g  = lds + m*KP;
    const float* wp = w + 2*o;
    float acc0 = bias[2*o];
    float acc1 = bias[2*o+1];
    int K4 = K & ~3;
    for (int k = 0; k < K4; k += 4){
        float4 g4 = *(const float4*)(g + k);
        float2 w0 = *(const float2*)(wp + (size_t)k    *O);
        float2 w1 = *(const float2*)(wp + (size_t)(k+1)*O);
        float2 w2 = *(const float2*)(wp + (size_t)(k+2)*O);
        float2 w3 = *(const float2*)(wp + (size_t)(k+3)*O);
        acc0 += g4.x*w0.x + g4.y*w1.x + g4.z*w2.x + g4.w*w3.x;
        acc1 += g4.x*w0.y + g4.y*w1.y + g4.z*w2.y + g4.w*w3.y;
    }
    for (int k = K4; k < K; k++){
        float gv = g[k];
        acc0 += gv * wp[(size_t)k*O];
        acc1 += gv * wp[(size_t)k*O + 1];
    }
    acc0 = acc0 > 0.f ? acc0 : __expf(acc0) - 1.f;
    acc1 = acc1 > 0.f ? acc1 : __expf(acc1) - 1.f;
    float2 r; r.x = acc0; r.y = acc1;
    *(float2*)(out + (size_t)gm*O + 2*o) = r;
}

// ---------- final conv (O=3, no ELU) + actor residual; bf16 input, 16-B gather ----------
__global__ __launch_bounds__(256) void k_outconv(const bf16* __restrict__ xin,
    const int* __restrict__ spiral, const float* __restrict__ w, const float* __restrict__ bias,
    const float* __restrict__ actor, float* __restrict__ out, int vshift, int bs)
{
    int t, rem; swz_t(blockIdx.x, bs, t, rem);
    int v = rem*256 + threadIdx.x;
    size_t i = ((size_t)t << vshift) + v;
    const bf16* xt = xin + (((size_t)t << vshift)) * 32;
    float a0 = bias[0], a1 = bias[1], a2 = bias[2];
    #pragma unroll
    for (int s = 0; s < 9; s++){
        int j = spiral[v*9 + s];
        const short8v* xr = (const short8v*)(xt + (size_t)j*32);
        #pragma unroll
        for (int h = 0; h < 4; h++){
            short8v sv = xr[h];
            const float* wr = w + (s*32 + h*8)*3;
            #pragma unroll
            for (int q = 0; q < 8; q++){
                float xv = bsu2f(sv[q]);
                a0 += xv * wr[q*3];
                a1 += xv * wr[q*3+1];
                a2 += xv * wr[q*3+2];
            }
        }
    }
    a0 += actor[v*3]; a1 += actor[v*3+1]; a2 += actor[v*3+2];
    out[i*3]   = a0;
    out[i*3+1] = a1;
    out[i*3+2] = a2;
}

extern "C" void kernel_launch(void* const* d_in, const int* in_sizes, int n_in,
                              void* d_out, int out_size, void* d_ws, size_t ws_size,
                              hipStream_t stream)
{
    (void)n_in; (void)out_size; (void)ws_size;
    const float* hs        = (const float*)d_in[0];
    const float* actor     = (const float*)d_in[1];
    const float* audio_w   = (const float*)d_in[2];
    const float* audio_b   = (const float*)d_in[3];
    const float* enc_w[4]  = {(const float*)d_in[4],(const float*)d_in[6],(const float*)d_in[8],(const float*)d_in[10]};
    const float* enc_b[4]  = {(const float*)d_in[5],(const float*)d_in[7],(const float*)d_in[9],(const float*)d_in[11]};
    const float* enc_lat_w = (const float*)d_in[12];
    const float* enc_lat_b = (const float*)d_in[13];
    const float* dec_lin_w = (const float*)d_in[14];
    const float* dec_lin_b = (const float*)d_in[15];
    const float* dec_w[4]  = {(const float*)d_in[16],(const float*)d_in[18],(const float*)d_in[20],(const float*)d_in[22]};
    const float* dec_b[4]  = {(const float*)d_in[17],(const float*)d_in[19],(const float*)d_in[21],(const float*)d_in[23]};
    const float* dec_out_w = (const float*)d_in[24];
    const float* dec_out_b = (const float*)d_in[25];
    const int*   spiral[4] = {(const int*)d_in[26],(const int*)d_in[27],(const int*)d_in[28],(const int*)d_in[29]};

    const int* dcol[4]; const float* dval[4]; const int* ucol[4]; const float* uval[4];
    bool interleaved = (in_sizes[33] == 3*8192);
    for (int i = 0; i < 4; i++){
        if (interleaved){
            int b = 30 + 6*i;
            dcol[i] = (const int*)d_in[b+1]; dval[i] = (const float*)d_in[b+2];
            ucol[i] = (const int*)d_in[b+4]; uval[i] = (const float*)d_in[b+5];
        } else {
            dcol[i] = (const int*)d_in[31+3*i]; dval[i] = (const float*)d_in[32+3*i];
            ucol[i] = (const int*)d_in[43+3*i]; uval[i] = (const float*)d_in[44+3*i];
        }
    }

    // ---- workspace ----
    char* ws = (char*)d_ws;
    size_t off = 0;
    auto alloc = [&](size_t bytes)->char* {
        char* p = ws + off; off += (bytes + 255) & ~(size_t)255; return p;
    };
    float* encX0 = (float*)alloc((size_t)262144*4);
    float* encP0 = (float*)alloc((size_t)65536*4);
    float* encX1 = (float*)alloc((size_t)131072*4);
    float* encP1 = (float*)alloc((size_t)32768*4);
    float* encX2 = (float*)alloc((size_t)32768*4);
    float* encP2 = (float*)alloc((size_t)8192*4);
    float* encX3 = (float*)alloc((size_t)16384*4);
    float* encP3 = (float*)alloc((size_t)4096*4);
    float* aemb  = (float*)alloc((size_t)4096*4);
    float* pemb  = (float*)alloc((size_t)64*4);
    short* wt0   = (short*)alloc((size_t)147456*2);   // dec0 [128][1152]
    short* wt1   = (short*)alloc((size_t)73728*2);    // dec1 [64][1152]
    short* wt2   = (short*)alloc((size_t)36864*2);    // dec2 [64][576]
    short* wt3   = (short*)alloc((size_t)18432*2);    // dec3 [32][576]
    char*  Praw  = alloc((size_t)36*1048576);         // conv outputs (f32 / bf16 views)
    bf16*  Qb    = (bf16*)alloc((size_t)68*1048576);  // pool outputs (bf16)
    float* P  = (float*)Praw;
    bf16*  Pb = (bf16*)Praw;

    // ---- prep ----
    k_audio<<<64,64,0,stream>>>(hs, audio_w, audio_b, aemb);
    k_wtr<<<576,256,0,stream>>>(dec_w[0], wt0, 1152, 128);
    k_wtr<<<288,256,0,stream>>>(dec_w[1], wt1, 1152, 64);
    k_wtr<<<144,256,0,stream>>>(dec_w[2], wt2, 576, 64);
    k_wtr<<<72,256,0,stream>>>(dec_w[3], wt3, 576, 32);

    // ---- encoder (VALU; tiny, B=1) ----
    k_conv<float><<<512,256, 16*28*4, stream>>>(actor, spiral[0], enc_w[0], enc_b[0], encX0, 8192, 8192,13,   3,16,4,  27,  28,16);
    k_pool4<float><<<64,256,0,stream>>>(encX0, dcol[0], dval[0], encP0, 16384, 7,3, 2047,11, 8192, -1,0);
    k_conv<float><<<256,256, 8*292*4, stream>>>(encP0, spiral[1], enc_w[1], enc_b[1], encX1, 2048, 2048,11,  32,32,5, 288, 292, 8);
    k_pool4<float><<<32,256,0,stream>>>(encX1, dcol[1], dval[1], encP1, 8192, 15,4, 511,9, 2048, -1,0);
    k_conv<float><<<64,256, 8*580*4, stream>>>(encP1, spiral[2], enc_w[2], enc_b[2], encX2, 512, 512,9,  64,32,5, 576, 580, 8);
    k_pool4<float><<<8,256,0,stream>>>(encX2, dcol[2], dval[2], encP2, 2048, 15,4, 127,7, 512, -1,0);
    k_conv<float><<<32,256, 4*580*4, stream>>>(encP2, spiral[3], enc_w[3], enc_b[3], encX3, 128, 128,7,  64,64,6, 576, 580, 4);
    k_pool4<float><<<4,256,0,stream>>>(encX3, dcol[3], dval[3], encP3, 1024, 31,5, 31,5, 128, -1,0);
    k_enclat<<<64,256,0,stream>>>(encP3, enc_lat_w, enc_lat_b, pemb);

    // ---- decoder (XCD t-swizzled, direct-A MFMA) ----
    k_declin4<<<dim3(4,64),256,0,stream>>>(aemb, pemb, dec_lin_w, dec_lin_b, P);  // [64,32,128] f32

    k_pool4<bf16><<<1024,256,0,stream>>>(P, ucol[3], uval[3], Qb, 262144, 31,5, 127,7, 32, 4, 4096);        // ->[64,128,128] bf16
    k_conv_dg<128,1152,7,7,float><<<256,256,0,stream>>>(Qb, spiral[3], wt0, dec_b[0], P, 2);                // ->[64,128,128] f32

    k_pool4<bf16><<<4096,256,0,stream>>>(P, ucol[2], uval[2], Qb, 1048576, 31,5, 511,9, 128, 6, 16384);     // ->[64,512,128] bf16
    k_conv_dg<64,1152,7,9,float><<<512,256,0,stream>>>(Qb, spiral[2], wt1, dec_b[1], P, 3);                 // ->[64,512,64] f32

    k_pool4<bf16><<<8192,256,0,stream>>>(P, ucol[1], uval[1], Qb, 2097152, 15,4, 2047,11, 512, 7, 32768);   // ->[64,2048,64] bf16
    k_conv_dg<64,576,6,11,float><<<2048,256,0,stream>>>(Qb, spiral[1], wt2, dec_b[2], P, 5);                // ->[64,2048,64] f32

    k_pool4<bf16><<<32768,256,0,stream>>>(P, ucol[0], uval[0], Qb, 8388608, 15,4, 8191,13, 2048, 9, 131072);// ->[64,8192,64] bf16
    k_conv_dg<32,576,6,13,bf16><<<4096,256,0,stream>>>(Qb, spiral[0], wt3, dec_b[3], Pb, 6);                // ->[64,8192,32] bf16

    k_outconv<<<2048,256,0,stream>>>(Pb, spiral[0], dec_out_w, dec_out_b, actor, (float*)d_out, 13, 5);
}